// Round 8
// baseline (588.399 us; speedup 1.0000x reference)
//
#include <hip/hip_runtime.h>
#include <stdint.h>

#define DD 256
#define NNODE 60000
#define MPAD 60032            // 469 * 128
#define NEDGE 200000
#define NGRAPH 1500
#define NCHUNK 59             // ceil(60000/1024)

typedef __bf16 bf16x8 __attribute__((ext_vector_type(8)));
typedef float f32x4 __attribute__((ext_vector_type(4)));
typedef unsigned short us8 __attribute__((ext_vector_type(8)));

__device__ __forceinline__ unsigned short f2bf(float f) {
    union { float f; unsigned int u; } v; v.f = f;
    unsigned int r = v.u + 0x7FFFu + ((v.u >> 16) & 1u);
    return (unsigned short)(r >> 16);
}
__device__ __forceinline__ float bf2f(unsigned short h) {
    union { unsigned int u; float f; } v; v.u = ((unsigned int)h) << 16;
    return v.f;
}
__device__ __forceinline__ void gload_lds16(const void* g, void* l) {
    __builtin_amdgcn_global_load_lds((const __attribute__((address_space(1))) void*)g,
                                     (__attribute__((address_space(3))) void*)l, 16, 0, 0);
}

// ---------------- weight prep: transposed bf16 weights ----------------
__global__ __launch_bounds__(256) void prep_weights(const float* __restrict__ mlpW,
                                                    const float* __restrict__ nnW,
                                                    const float* __restrict__ aW,
                                                    const float* __restrict__ ab,
                                                    unsigned short* __restrict__ wc1,
                                                    unsigned short* __restrict__ wc2,
                                                    unsigned short* __restrict__ nnt,
                                                    unsigned short* __restrict__ aWt) {
    int idx = blockIdx.x * 256 + threadIdx.x;
    if (idx < 256 * 512) {
        int n = idx >> 9, k = idx & 511;
        float v1 = (k < 256) ? mlpW[k * DD + n] : mlpW[(k + 256) * DD + n];
        wc1[idx] = f2bf(v1);
        wc2[idx] = f2bf(mlpW[(k + 256) * DD + n]);
    }
    if (idx < 256 * 256) {
        int n = idx >> 8, k = idx & 255;
        nnt[idx] = f2bf(nnW[k * DD + n]);
    }
    if (idx < 256 * 96) {
        int n = idx / 96, k = idx - n * 96;
        float v = (k < 92) ? aW[k * DD + n] : (k == 92 ? ab[n] : 0.0f);
        aWt[idx] = f2bf(v);
    }
}

// ---------------- u/v chains + BN fold ----------------
__global__ __launch_bounds__(256) void prep_uv(const float* __restrict__ eW, const float* __restrict__ eb,
                                               const float* __restrict__ mlpW, const float* __restrict__ mlpb,
                                               const float* __restrict__ nnb,
                                               const float* __restrict__ bn_g, const float* __restrict__ bn_b,
                                               const float* __restrict__ bn_m, const float* __restrict__ bn_v,
                                               float* __restrict__ u_all, float* __restrict__ v_all,
                                               float* __restrict__ scale, float* __restrict__ shift) {
    __shared__ float uc[DD], vc[DD];
    int d = threadIdx.x;
    uc[d] = eW[d];
    vc[d] = eb[d];
    float sc = bn_g[d] * rsqrtf(bn_v[d] + 1e-5f);
    scale[d] = sc;
    shift[d] = (nnb[d] - bn_m[d]) * sc + bn_b[d];
    __syncthreads();
    const float* W3 = mlpW + 2 * DD * DD;
    for (int it = 0; it < 4; ++it) {
        float su = 0.f, sv = 0.f;
        for (int k = 0; k < DD; ++k) {
            float w = W3[k * DD + d];
            su += uc[k] * w;
            sv += vc[k] * w;
        }
        sv += mlpb[d];
        u_all[it * DD + d] = su;
        v_all[it * DD + d] = sv;
        __syncthreads();
        uc[d] = su; vc[d] = sv;
        __syncthreads();
    }
}

// ---------------- nf -> bf16 padded [MPAD][96] with bias column ----------------
__global__ __launch_bounds__(256) void nfb_prep(const float* __restrict__ nf, unsigned short* __restrict__ nfb) {
    int idx = blockIdx.x * 256 + threadIdx.x;
    if (idx >= MPAD * 96) return;
    int r = idx / 96, c = idx - r * 96;
    float v;
    if (r < NNODE && c < 92) v = nf[(size_t)r * 92 + c];
    else v = (c == 92) ? 1.0f : 0.0f;
    nfb[idx] = f2bf(v);
}

// ---------------- xinit GEMM: x[M][256] = nfb[M][96] @ aWt^T, single-stage ----------------
__global__ __launch_bounds__(512) void xinit_gemm(const unsigned short* __restrict__ nfb,
                                                  const unsigned short* __restrict__ aWt,
                                                  unsigned short* __restrict__ x) {
    __shared__ unsigned short shmem[(128 + 256) * 96];
    unsigned short (*As)[96] = (unsigned short(*)[96])shmem;
    unsigned short (*Bs)[96] = (unsigned short(*)[96])(shmem + 128 * 96);
    const int tid = threadIdx.x;
    const int lane = tid & 63, wid = tid >> 6;
    const int wr = wid >> 2, wc = wid & 3;
    const int m0 = blockIdx.x * 128;
    const int lr = lane & 15, lq = lane >> 4;

    for (int i = tid; i < 128 * 12; i += 512) {
        int row = i / 12, ch = (i - row * 12) * 8;
        gload_lds16(nfb + (size_t)(m0 + row) * 96 + ch, &As[row][ch]);
    }
    for (int i = tid; i < 256 * 12; i += 512) {
        int row = i / 12, ch = (i - row * 12) * 8;
        gload_lds16(aWt + (size_t)row * 96 + ch, &Bs[row][ch]);
    }
    __syncthreads();

    f32x4 acc[4][4];
    #pragma unroll
    for (int m = 0; m < 4; ++m)
        #pragma unroll
        for (int n = 0; n < 4; ++n) { f32x4 z = {0.f,0.f,0.f,0.f}; acc[m][n] = z; }

    #pragma unroll
    for (int h = 0; h < 3; ++h) {
        bf16x8 af[4], bf[4];
        #pragma unroll
        for (int m = 0; m < 4; ++m)
            af[m] = *reinterpret_cast<const bf16x8*>(&As[wr * 64 + m * 16 + lr][h * 32 + lq * 8]);
        #pragma unroll
        for (int n = 0; n < 4; ++n)
            bf[n] = *reinterpret_cast<const bf16x8*>(&Bs[wc * 64 + n * 16 + lr][h * 32 + lq * 8]);
        #pragma unroll
        for (int m = 0; m < 4; ++m)
            #pragma unroll
            for (int n = 0; n < 4; ++n)
                acc[m][n] = __builtin_amdgcn_mfma_f32_16x16x32_bf16(af[m], bf[n], acc[m][n], 0, 0, 0);
    }
    __syncthreads();

    // LDS-staged coalesced epilogue
    unsigned short* stg = shmem;
    #pragma unroll
    for (int half = 0; half < 2; ++half) {
        if (wr == half) {
            #pragma unroll
            for (int m = 0; m < 4; ++m)
                #pragma unroll
                for (int n = 0; n < 4; ++n) {
                    const int cs = (wc * 64 + n * 16 + lr) ^ (lq << 4);
                    #pragma unroll
                    for (int j = 0; j < 4; ++j)
                        stg[(m * 16 + lq * 4 + j) * 256 + cs] = f2bf(acc[m][n][j]);
                }
        }
        __syncthreads();
        const int rbase = m0 + half * 64;
        #pragma unroll
        for (int t = 0; t < 4; ++t) {
            int tt = tid + t * 512;
            int rl = tt >> 5, ch = tt & 31;
            int chs = ch ^ (((rl >> 2) & 3) << 1);
            us8 pv = *(const us8*)&stg[rl * 256 + chs * 8];
            ((us8*)x)[(size_t)(rbase + rl) * 32 + ch] = pv;
        }
        __syncthreads();
    }
}

// ---------------- CSR build ----------------
__global__ __launch_bounds__(256) void hist_kernel(const int* __restrict__ ei, int* __restrict__ counts) {
    int e = blockIdx.x * 256 + threadIdx.x;
    if (e < NEDGE) atomicAdd(&counts[ei[NEDGE + e]], 1);
}

__global__ __launch_bounds__(256) void scan1(const int* __restrict__ counts, int* __restrict__ blockSums) {
    int t = threadIdx.x;
    int base = blockIdx.x * 1024 + t * 4;
    int s = 0;
    #pragma unroll
    for (int i = 0; i < 4; ++i) { int idx = base + i; if (idx < NNODE) s += counts[idx]; }
    __shared__ int red[256];
    red[t] = s; __syncthreads();
    for (int d = 128; d; d >>= 1) { if (t < d) red[t] += red[t + d]; __syncthreads(); }
    if (t == 0) blockSums[blockIdx.x] = red[0];
}

__global__ __launch_bounds__(64) void scan2(int* __restrict__ blockSums) {
    int t = threadIdx.x;
    int v = (t < NCHUNK) ? blockSums[t] : 0;
    int orig = v;
    #pragma unroll
    for (int d = 1; d < 64; d <<= 1) {
        int o = __shfl_up(v, d);
        if (t >= d) v += o;
    }
    if (t < NCHUNK) blockSums[t] = v - orig;   // exclusive
}

__global__ __launch_bounds__(256) void scan3(const int* __restrict__ counts, const int* __restrict__ blockSums,
                                             int* __restrict__ offsets, int* __restrict__ cursor) {
    int t = threadIdx.x;
    int base = blockIdx.x * 1024 + t * 4;
    int c[4]; int s = 0;
    #pragma unroll
    for (int i = 0; i < 4; ++i) { int idx = base + i; c[i] = (idx < NNODE) ? counts[idx] : 0; s += c[i]; }
    __shared__ int lds[256];
    lds[t] = s; __syncthreads();
    for (int d = 1; d < 256; d <<= 1) {
        int v = (t >= d) ? lds[t - d] : 0;
        __syncthreads();
        lds[t] += v;
        __syncthreads();
    }
    int off = blockSums[blockIdx.x] + lds[t] - s;
    #pragma unroll
    for (int i = 0; i < 4; ++i) {
        int idx = base + i;
        if (idx < NNODE) { offsets[idx] = off; cursor[idx] = off; off += c[i]; }
    }
}

__global__ __launch_bounds__(256) void scatter_kernel(const int* __restrict__ ei, const float* __restrict__ aw,
                                                      int* __restrict__ cursor,
                                                      int* __restrict__ srow, float* __restrict__ sw) {
    int e = blockIdx.x * 256 + threadIdx.x;
    if (e < NEDGE) {
        int c = ei[NEDGE + e];
        int pos = atomicAdd(&cursor[c], 1);
        srow[pos] = ei[e];
        sw[pos] = aw[e];
    }
}

// ---------------- merged P/Q GEMM, BK=32 double-buffered pipeline ----------------
// LDS: 2 bufs x (A 128x32 + B 256x32) bf16 = 48 KB -> 3 blocks/CU.
// Per K-step: issue STAGE(t+1 -> buf^1) first, ds_read+MFMA on buf, own-vmcnt(0),
// raw s_barrier (one barrier/step; after it ALL waves' stages are visible).
// Bank swizzle: chunk' = chunk ^ ((row>>1)&3) (full 32-bank coverage per 8 lanes);
// write side pre-swizzles the GLOBAL source, gload_lds dest stays linear.
__global__ __launch_bounds__(512) void gemm_pq(const unsigned short* __restrict__ X,
                                               const unsigned short* __restrict__ Pst,
                                               const unsigned short* __restrict__ Qst,
                                               const unsigned short* __restrict__ B1,
                                               const unsigned short* __restrict__ B2,
                                               unsigned short* __restrict__ Pout,
                                               unsigned short* __restrict__ PXout,
                                               unsigned short* __restrict__ Qout,
                                               const float* __restrict__ cq,
                                               int Ktot) {
    __shared__ unsigned short shmem[2 * 384 * 32];   // 48 KB
    const int b = blockIdx.x;
    const int pairb = b >> 4, jj = b & 15;
    const int sel = jj >> 3, sub = jj & 7;
    const int mb = pairb * 8 + sub;
    if (mb >= MPAD / 128) return;
    const int m0 = mb * 128;

    const unsigned short* A1 = sel ? Qst : Pst;
    const unsigned short* Bt = sel ? B2 : B1;

    const int tid = threadIdx.x;
    const int lane = tid & 63, wid = tid >> 6;
    const int wr = wid >> 2, wc = wid & 3;
    const int lr = lane & 15, lq = lane >> 4;
    const int srowA = tid >> 2;               // 0..127
    const int jphys = tid & 3;                // 16B chunk in 32-col row
    const int jlogA = jphys ^ ((srowA >> 1) & 3);

    // stage helpers: buf region = shmem + buf*12288 (A at 0, B at 4096 shorts)
    auto stage = [&](int kt, int buf) {
        const int k0 = kt << 5;
        const unsigned short* Ap; int ka;
        if (k0 < 256) { Ap = X; ka = k0; } else { Ap = A1; ka = k0 - 256; }
        unsigned short* base = shmem + buf * 12288;
        gload_lds16(Ap + (size_t)(m0 + srowA) * DD + ka + jlogA * 8, base + srowA * 32 + jphys * 8);
        #pragma unroll
        for (int p = 0; p < 2; ++p) {
            int row = p * 128 + srowA;
            gload_lds16(Bt + (size_t)row * 512 + k0 + jlogA * 8, base + 4096 + row * 32 + jphys * 8);
        }
    };

    f32x4 acc[4][4];
    #pragma unroll
    for (int m = 0; m < 4; ++m)
        #pragma unroll
        for (int n = 0; n < 4; ++n) { f32x4 z = {0.f,0.f,0.f,0.f}; acc[m][n] = z; }

    const int nk = Ktot >> 5;
    // prologue
    stage(0, 0);
    asm volatile("s_waitcnt vmcnt(0)" ::: "memory");
    __builtin_amdgcn_sched_barrier(0);
    __builtin_amdgcn_s_barrier();

    for (int kt = 0; kt < nk; ++kt) {
        const int cur = kt & 1;
        if (kt + 1 < nk) stage(kt + 1, cur ^ 1);
        __builtin_amdgcn_sched_barrier(0);
        const unsigned short* base = shmem + cur * 12288;
        bf16x8 af[4], bfr[4];
        #pragma unroll
        for (int m = 0; m < 4; ++m) {
            int r = wr * 64 + m * 16 + lr;
            af[m] = *reinterpret_cast<const bf16x8*>(base + r * 32 + ((lq ^ ((r >> 1) & 3)) << 3));
        }
        #pragma unroll
        for (int n = 0; n < 4; ++n) {
            int r = wc * 64 + n * 16 + lr;
            bfr[n] = *reinterpret_cast<const bf16x8*>(base + 4096 + r * 32 + ((lq ^ ((r >> 1) & 3)) << 3));
        }
        #pragma unroll
        for (int m = 0; m < 4; ++m)
            #pragma unroll
            for (int n = 0; n < 4; ++n)
                acc[m][n] = __builtin_amdgcn_mfma_f32_16x16x32_bf16(af[m], bfr[n], acc[m][n], 0, 0, 0);
        asm volatile("s_waitcnt vmcnt(0)" ::: "memory");
        __builtin_amdgcn_sched_barrier(0);
        __builtin_amdgcn_s_barrier();
    }

    // ---- LDS-staged coalesced epilogue (stg = 64x256 = 32 KB in shmem) ----
    float cqv[4];
    if (sel) {
        #pragma unroll
        for (int n = 0; n < 4; ++n) cqv[n] = cq[wc * 64 + n * 16 + lr];
    }
    unsigned short* stg = shmem;
    #pragma unroll
    for (int half = 0; half < 2; ++half) {
        if (wr == half) {
            #pragma unroll
            for (int m = 0; m < 4; ++m)
                #pragma unroll
                for (int n = 0; n < 4; ++n) {
                    const int cs = (wc * 64 + n * 16 + lr) ^ (lq << 4);
                    #pragma unroll
                    for (int j = 0; j < 4; ++j) {
                        float v = acc[m][n][j];
                        if (sel) v += cqv[n];
                        stg[(m * 16 + lq * 4 + j) * 256 + cs] = f2bf(v);
                    }
                }
        }
        __syncthreads();
        const int rbase = m0 + half * 64;
        #pragma unroll
        for (int t = 0; t < 4; ++t) {
            int tt = tid + t * 512;
            int rl = tt >> 5, ch = tt & 31;
            int chs = ch ^ (((rl >> 2) & 3) << 1);
            us8 pv = *(const us8*)&stg[rl * 256 + chs * 8];
            size_t gidx = (size_t)(rbase + rl) * 32 + ch;
            if (sel == 0) {
                us8 xv = ((const us8*)X)[gidx];
                us8 o;
                #pragma unroll
                for (int c = 0; c < 8; ++c) o[c] = f2bf(bf2f(pv[c]) + bf2f(xv[c]));
                ((us8*)Pout)[gidx] = pv;
                ((us8*)PXout)[gidx] = o;
            } else {
                ((us8*)Qout)[gidx] = pv;
            }
        }
        __syncthreads();
    }
}

// ---------------- BN GEMM: x = relu((aggB @ nnt^T)*scale+shift), BK=32 pipelined ----------------
__global__ __launch_bounds__(512) void gemm_bn(const unsigned short* __restrict__ A,
                                               const unsigned short* __restrict__ Bt,
                                               unsigned short* __restrict__ Cout,
                                               const float* __restrict__ scale,
                                               const float* __restrict__ shift) {
    __shared__ unsigned short shmem[2 * 384 * 32];
    const int tid = threadIdx.x;
    const int lane = tid & 63, wid = tid >> 6;
    const int wr = wid >> 2, wc = wid & 3;
    const int m0 = blockIdx.x * 128;
    const int lr = lane & 15, lq = lane >> 4;
    const int srowA = tid >> 2;
    const int jphys = tid & 3;
    const int jlogA = jphys ^ ((srowA >> 1) & 3);

    auto stage = [&](int kt, int buf) {
        const int k0 = kt << 5;
        unsigned short* base = shmem + buf * 12288;
        gload_lds16(A + (size_t)(m0 + srowA) * DD + k0 + jlogA * 8, base + srowA * 32 + jphys * 8);
        #pragma unroll
        for (int p = 0; p < 2; ++p) {
            int row = p * 128 + srowA;
            gload_lds16(Bt + (size_t)row * DD + k0 + jlogA * 8, base + 4096 + row * 32 + jphys * 8);
        }
    };

    f32x4 acc[4][4];
    #pragma unroll
    for (int m = 0; m < 4; ++m)
        #pragma unroll
        for (int n = 0; n < 4; ++n) { f32x4 z = {0.f,0.f,0.f,0.f}; acc[m][n] = z; }

    const int nk = 8;   // K = 256
    stage(0, 0);
    asm volatile("s_waitcnt vmcnt(0)" ::: "memory");
    __builtin_amdgcn_sched_barrier(0);
    __builtin_amdgcn_s_barrier();

    for (int kt = 0; kt < nk; ++kt) {
        const int cur = kt & 1;
        if (kt + 1 < nk) stage(kt + 1, cur ^ 1);
        __builtin_amdgcn_sched_barrier(0);
        const unsigned short* base = shmem + cur * 12288;
        bf16x8 af[4], bfr[4];
        #pragma unroll
        for (int m = 0; m < 4; ++m) {
            int r = wr * 64 + m * 16 + lr;
            af[m] = *reinterpret_cast<const bf16x8*>(base + r * 32 + ((lq ^ ((r >> 1) & 3)) << 3));
        }
        #pragma unroll
        for (int n = 0; n < 4; ++n) {
            int r = wc * 64 + n * 16 + lr;
            bfr[n] = *reinterpret_cast<const bf16x8*>(base + 4096 + r * 32 + ((lq ^ ((r >> 1) & 3)) << 3));
        }
        #pragma unroll
        for (int m = 0; m < 4; ++m)
            #pragma unroll
            for (int n = 0; n < 4; ++n)
                acc[m][n] = __builtin_amdgcn_mfma_f32_16x16x32_bf16(af[m], bfr[n], acc[m][n], 0, 0, 0);
        asm volatile("s_waitcnt vmcnt(0)" ::: "memory");
        __builtin_amdgcn_sched_barrier(0);
        __builtin_amdgcn_s_barrier();
    }

    float scl[4], shf[4];
    #pragma unroll
    for (int n = 0; n < 4; ++n) {
        int c = wc * 64 + n * 16 + lr;
        scl[n] = scale[c]; shf[n] = shift[c];
    }
    unsigned short* stg = shmem;
    #pragma unroll
    for (int half = 0; half < 2; ++half) {
        if (wr == half) {
            #pragma unroll
            for (int m = 0; m < 4; ++m)
                #pragma unroll
                for (int n = 0; n < 4; ++n) {
                    const int cs = (wc * 64 + n * 16 + lr) ^ (lq << 4);
                    #pragma unroll
                    for (int j = 0; j < 4; ++j) {
                        float y = fmaxf(acc[m][n][j] * scl[n] + shf[n], 0.f);
                        stg[(m * 16 + lq * 4 + j) * 256 + cs] = f2bf(y);
                    }
                }
        }
        __syncthreads();
        const int rbase = m0 + half * 64;
        #pragma unroll
        for (int t = 0; t < 4; ++t) {
            int tt = tid + t * 512;
            int rl = tt >> 5, ch = tt & 31;
            int chs = ch ^ (((rl >> 2) & 3) << 1);
            us8 pv = *(const us8*)&stg[rl * 256 + chs * 8];
            ((us8*)Cout)[(size_t)(rbase + rl) * 32 + ch] = pv;
        }
        __syncthreads();
    }
}

// ---------------- edge pass (CSR gather, single-gather): one wave per node ----------------
// aggB[n] = x[n] + sum_{e: col(e)=n} relu( PX[r] + Qv[n] + w*u )
__global__ __launch_bounds__(256) void edge_csr(const int* __restrict__ offsets, const int* __restrict__ counts,
                                                const int* __restrict__ srow, const float* __restrict__ sw,
                                                const unsigned short* __restrict__ X,
                                                const unsigned short* __restrict__ PX,
                                                const unsigned short* __restrict__ Qv,
                                                const float* __restrict__ u,
                                                unsigned short* __restrict__ aggB) {
    const int lane = threadIdx.x & 63, wid = threadIdx.x >> 6;
    const int n = blockIdx.x * 4 + wid;
    if (n >= NNODE) return;
    const int start = offsets[n];
    const int deg = counts[n];
    const int sub = lane & 31, h = lane >> 5;

    const us8* PX8 = (const us8*)PX;

    float4 u0 = ((const float4*)u)[sub * 2], u1 = ((const float4*)u)[sub * 2 + 1];
    float uu[8] = {u0.x, u0.y, u0.z, u0.w, u1.x, u1.y, u1.z, u1.w};

    us8 qv = ((const us8*)Qv)[(size_t)n * 32 + sub];
    float qb[8];
    #pragma unroll
    for (int c = 0; c < 8; ++c) qb[c] = bf2f(qv[c]);

    float a[8];
    us8 xv = ((const us8*)X)[(size_t)n * 32 + sub];
    #pragma unroll
    for (int c = 0; c < 8; ++c) a[c] = (h == 0) ? bf2f(xv[c]) : 0.f;

    for (int b0 = 0; b0 < deg; b0 += 64) {
        int m = deg - b0; if (m > 64) m = 64;
        int myr = 0; float myw = 0.f;
        if (lane < m) { myr = srow[start + b0 + lane]; myw = sw[start + b0 + lane]; }
        int iters = (m + 1) >> 1;
        for (int j = 0; j < iters; ++j) {
            int el = 2 * j + h;
            int r = __shfl(myr, el);
            float w = __shfl(myw, el);
            if (el < m) {
                us8 p2 = PX8[(size_t)r * 32 + sub];
                #pragma unroll
                for (int c = 0; c < 8; ++c)
                    a[c] += fmaxf(bf2f(p2[c]) + qb[c] + w * uu[c], 0.f);
            }
        }
    }
    #pragma unroll
    for (int c = 0; c < 8; ++c) a[c] += __shfl_xor(a[c], 32);
    if (h == 0) {
        us8 o;
        #pragma unroll
        for (int c = 0; c < 8; ++c) o[c] = f2bf(a[c]);
        ((us8*)aggB)[(size_t)n * 32 + sub] = o;
    }
}

// ---------------- pooling: pooled[batch[n]] += x[n], batch sorted ----------------
__global__ __launch_bounds__(256) void pool_kernel(const unsigned short* __restrict__ x,
                                                   const int* __restrict__ batch,
                                                   float* __restrict__ pooled) {
    const int lane = threadIdx.x & 63, wid = threadIdx.x >> 6;
    const int base = (blockIdx.x * 4 + wid) * 8;
    float4 acc = make_float4(0.f, 0.f, 0.f, 0.f);
    int gcur = -1;
    for (int i = 0; i < 8; ++i) {
        int n = base + i;
        if (n >= NNODE) break;
        int g = batch[n];
        if (g != gcur) {
            if (gcur >= 0) {
                float* pp = pooled + (size_t)gcur * DD + lane * 4;
                unsafeAtomicAdd(pp + 0, acc.x);
                unsafeAtomicAdd(pp + 1, acc.y);
                unsafeAtomicAdd(pp + 2, acc.z);
                unsafeAtomicAdd(pp + 3, acc.w);
            }
            gcur = g;
            acc = make_float4(0.f, 0.f, 0.f, 0.f);
        }
        ushort4 xv = ((const ushort4*)x)[(size_t)n * 64 + lane];
        acc.x += bf2f(xv.x); acc.y += bf2f(xv.y);
        acc.z += bf2f(xv.z); acc.w += bf2f(xv.w);
    }
    if (gcur >= 0) {
        float* pp = pooled + (size_t)gcur * DD + lane * 4;
        unsafeAtomicAdd(pp + 0, acc.x);
        unsafeAtomicAdd(pp + 1, acc.y);
        unsafeAtomicAdd(pp + 2, acc.z);
        unsafeAtomicAdd(pp + 3, acc.w);
    }
}

// ---------------- out: d_out = pooled @ outW + outb ----------------
__global__ __launch_bounds__(64) void out_kernel(const float* __restrict__ pooled,
                                                 const float* __restrict__ outW,
                                                 const float* __restrict__ outb,
                                                 float* __restrict__ out) {
    const int g = blockIdx.x, lane = threadIdx.x;
    float4 p = ((const float4*)pooled)[g * 64 + lane];
    float s[6];
    #pragma unroll
    for (int j = 0; j < 6; ++j) {
        float a = p.x * outW[(lane * 4 + 0) * 6 + j] + p.y * outW[(lane * 4 + 1) * 6 + j] +
                  p.z * outW[(lane * 4 + 2) * 6 + j] + p.w * outW[(lane * 4 + 3) * 6 + j];
        #pragma unroll
        for (int off = 32; off; off >>= 1) a += __shfl_down(a, off);
        s[j] = a;
    }
    if (lane == 0) {
        #pragma unroll
        for (int j = 0; j < 6; ++j) out[g * 6 + j] = s[j] + outb[j];
    }
}

extern "C" void kernel_launch(void* const* d_in, const int* in_sizes, int n_in,
                              void* d_out, int out_size, void* d_ws, size_t ws_size,
                              hipStream_t stream) {
    const float* nf    = (const float*)d_in[0];
    const int*   ei    = (const int*)d_in[1];
    const float* aw    = (const float*)d_in[2];
    const int*   batch = (const int*)d_in[3];
    const float* aW    = (const float*)d_in[4];
    const float* ab    = (const float*)d_in[5];
    const float* eW    = (const float*)d_in[6];
    const float* eb    = (const float*)d_in[7];
    const float* mlpW  = (const float*)d_in[8];
    const float* mlpb  = (const float*)d_in[9];
    const float* nnW   = (const float*)d_in[10];
    const float* nnb   = (const float*)d_in[11];
    const float* bn_g  = (const float*)d_in[12];
    const float* bn_b  = (const float*)d_in[13];
    const float* bn_m  = (const float*)d_in[14];
    const float* bn_v  = (const float*)d_in[15];
    const float* outW  = (const float*)d_in[16];
    const float* outb  = (const float*)d_in[17];
    float* out = (float*)d_out;

    char* ws = (char*)d_ws;
    size_t off = 0;
    auto alloc = [&](size_t bytes) -> void* {
        void* p = ws + off;
        off += (bytes + 255) & ~(size_t)255;
        return p;
    };
    unsigned short* x    = (unsigned short*)alloc((size_t)MPAD * DD * 2);
    unsigned short* P    = (unsigned short*)alloc((size_t)MPAD * DD * 2);
    unsigned short* Qv   = (unsigned short*)alloc((size_t)MPAD * DD * 2);
    unsigned short* aggB = (unsigned short*)alloc((size_t)MPAD * DD * 2);
    // PX shares its region with nfb (nfb dead after xinit; PX written from layer 0 on)
    unsigned short* PX   = (unsigned short*)alloc((size_t)MPAD * DD * 2);
    unsigned short* nfb  = PX;   // MPAD*96*2 < MPAD*DD*2, alias is safe
    unsigned short* wc1  = (unsigned short*)alloc(256 * 512 * 2);
    unsigned short* wc2  = (unsigned short*)alloc(256 * 512 * 2);
    unsigned short* nnt  = (unsigned short*)alloc(256 * 256 * 2);
    unsigned short* aWt  = (unsigned short*)alloc(256 * 96 * 2);
    float* u_all = (float*)alloc(4 * DD * 4);
    float* v_all = (float*)alloc(4 * DD * 4);
    float* scale = (float*)alloc(DD * 4);
    float* shift = (float*)alloc(DD * 4);
    float* pooled = (float*)alloc((size_t)NGRAPH * DD * 4);
    int* counts  = (int*)alloc((size_t)NNODE * 4);
    int* offsets = (int*)alloc((size_t)NNODE * 4);
    int* cursor  = (int*)alloc((size_t)NNODE * 4);
    int* blockSums = (int*)alloc(NCHUNK * 4);
    int* srowB   = (int*)alloc((size_t)NEDGE * 4);
    float* swB   = (float*)alloc((size_t)NEDGE * 4);
    (void)ws_size; (void)in_sizes; (void)n_in; (void)out_size;

    // one-time prep
    prep_weights<<<512, 256, 0, stream>>>(mlpW, nnW, aW, ab, wc1, wc2, nnt, aWt);
    prep_uv<<<1, 256, 0, stream>>>(eW, eb, mlpW, mlpb, nnb, bn_g, bn_b, bn_m, bn_v,
                                   u_all, v_all, scale, shift);
    nfb_prep<<<(MPAD * 96 + 255) / 256, 256, 0, stream>>>(nf, nfb);
    xinit_gemm<<<MPAD / 128, 512, 0, stream>>>(nfb, aWt, x);

    // CSR build (once; shared by all 4 layers)
    hipMemsetAsync(counts, 0, (size_t)NNODE * 4, stream);
    hist_kernel<<<(NEDGE + 255) / 256, 256, 0, stream>>>(ei, counts);
    scan1<<<NCHUNK, 256, 0, stream>>>(counts, blockSums);
    scan2<<<1, 64, 0, stream>>>(blockSums);
    scan3<<<NCHUNK, 256, 0, stream>>>(counts, blockSums, offsets, cursor);
    scatter_kernel<<<(NEDGE + 255) / 256, 256, 0, stream>>>(ei, aw, cursor, srowB, swB);

    const int npairs = (MPAD / 128 + 7) / 8;   // 59
    for (int k = 0; k < 4; ++k) {
        gemm_pq<<<npairs * 16, 512, 0, stream>>>(x, P, Qv, wc1, wc2, P, PX, Qv,
                                                 k == 0 ? v_all : mlpb, k ? 512 : 256);
        edge_csr<<<(NNODE + 3) / 4, 256, 0, stream>>>(offsets, counts, srowB, swB, x, PX, Qv,
                                                      u_all + k * DD, aggB);
        gemm_bn<<<MPAD / 128, 512, 0, stream>>>(aggB, nnt, x, scale, shift);
    }

    hipMemsetAsync(pooled, 0, (size_t)NGRAPH * DD * 4, stream);
    pool_kernel<<<(NNODE + 31) / 32, 256, 0, stream>>>(x, batch, pooled);
    out_kernel<<<NGRAPH, 64, 0, stream>>>(pooled, outW, outb, out);
}

// Round 9
// 541.800 us; speedup vs baseline: 1.0860x; 1.0860x over previous
//
#include <hip/hip_runtime.h>
#include <stdint.h>

#define DD 256
#define NNODE 60000
#define MPAD 60032            // 469 * 128 = 938 * 64
#define NEDGE 200000
#define NGRAPH 1500
#define NCHUNK 59             // ceil(60000/1024)

typedef __bf16 bf16x8 __attribute__((ext_vector_type(8)));
typedef float f32x4 __attribute__((ext_vector_type(4)));
typedef unsigned short us8 __attribute__((ext_vector_type(8)));

__device__ __forceinline__ unsigned short f2bf(float f) {
    union { float f; unsigned int u; } v; v.f = f;
    unsigned int r = v.u + 0x7FFFu + ((v.u >> 16) & 1u);
    return (unsigned short)(r >> 16);
}
__device__ __forceinline__ float bf2f(unsigned short h) {
    union { unsigned int u; float f; } v; v.u = ((unsigned int)h) << 16;
    return v.f;
}
__device__ __forceinline__ void gload_lds16(const void* g, void* l) {
    __builtin_amdgcn_global_load_lds((const __attribute__((address_space(1))) void*)g,
                                     (__attribute__((address_space(3))) void*)l, 16, 0, 0);
}

// ---------------- weight prep: transposed bf16 weights ----------------
__global__ __launch_bounds__(256) void prep_weights(const float* __restrict__ mlpW,
                                                    const float* __restrict__ nnW,
                                                    const float* __restrict__ aW,
                                                    const float* __restrict__ ab,
                                                    unsigned short* __restrict__ wc1,
                                                    unsigned short* __restrict__ wc2,
                                                    unsigned short* __restrict__ nnt,
                                                    unsigned short* __restrict__ aWt) {
    int idx = blockIdx.x * 256 + threadIdx.x;
    if (idx < 256 * 512) {
        int n = idx >> 9, k = idx & 511;
        float v1 = (k < 256) ? mlpW[k * DD + n] : mlpW[(k + 256) * DD + n];
        wc1[idx] = f2bf(v1);
        wc2[idx] = f2bf(mlpW[(k + 256) * DD + n]);
    }
    if (idx < 256 * 256) {
        int n = idx >> 8, k = idx & 255;
        nnt[idx] = f2bf(nnW[k * DD + n]);
    }
    if (idx < 256 * 96) {
        int n = idx / 96, k = idx - n * 96;
        float v = (k < 92) ? aW[k * DD + n] : (k == 92 ? ab[n] : 0.0f);
        aWt[idx] = f2bf(v);
    }
}

// ---------------- u/v chains + BN fold ----------------
__global__ __launch_bounds__(256) void prep_uv(const float* __restrict__ eW, const float* __restrict__ eb,
                                               const float* __restrict__ mlpW, const float* __restrict__ mlpb,
                                               const float* __restrict__ nnb,
                                               const float* __restrict__ bn_g, const float* __restrict__ bn_b,
                                               const float* __restrict__ bn_m, const float* __restrict__ bn_v,
                                               float* __restrict__ u_all, float* __restrict__ v_all,
                                               float* __restrict__ scale, float* __restrict__ shift) {
    __shared__ float uc[DD], vc[DD];
    int d = threadIdx.x;
    uc[d] = eW[d];
    vc[d] = eb[d];
    float sc = bn_g[d] * rsqrtf(bn_v[d] + 1e-5f);
    scale[d] = sc;
    shift[d] = (nnb[d] - bn_m[d]) * sc + bn_b[d];
    __syncthreads();
    const float* W3 = mlpW + 2 * DD * DD;
    for (int it = 0; it < 4; ++it) {
        float su = 0.f, sv = 0.f;
        for (int k = 0; k < DD; ++k) {
            float w = W3[k * DD + d];
            su += uc[k] * w;
            sv += vc[k] * w;
        }
        sv += mlpb[d];
        u_all[it * DD + d] = su;
        v_all[it * DD + d] = sv;
        __syncthreads();
        uc[d] = su; vc[d] = sv;
        __syncthreads();
    }
}

// ---------------- nf -> bf16 padded [MPAD][96] with bias column ----------------
__global__ __launch_bounds__(256) void nfb_prep(const float* __restrict__ nf, unsigned short* __restrict__ nfb) {
    int idx = blockIdx.x * 256 + threadIdx.x;
    if (idx >= MPAD * 96) return;
    int r = idx / 96, c = idx - r * 96;
    float v;
    if (r < NNODE && c < 92) v = nf[(size_t)r * 92 + c];
    else v = (c == 92) ? 1.0f : 0.0f;
    nfb[idx] = f2bf(v);
}

// ---------------- xinit GEMM: x[M][256] = nfb[M][96] @ aWt^T, single-stage ----------------
__global__ __launch_bounds__(512) void xinit_gemm(const unsigned short* __restrict__ nfb,
                                                  const unsigned short* __restrict__ aWt,
                                                  unsigned short* __restrict__ x) {
    __shared__ unsigned short shmem[(128 + 256) * 96];
    unsigned short (*As)[96] = (unsigned short(*)[96])shmem;
    unsigned short (*Bs)[96] = (unsigned short(*)[96])(shmem + 128 * 96);
    const int tid = threadIdx.x;
    const int lane = tid & 63, wid = tid >> 6;
    const int wr = wid >> 2, wc = wid & 3;
    const int m0 = blockIdx.x * 128;
    const int lr = lane & 15, lq = lane >> 4;

    for (int i = tid; i < 128 * 12; i += 512) {
        int row = i / 12, ch = (i - row * 12) * 8;
        gload_lds16(nfb + (size_t)(m0 + row) * 96 + ch, &As[row][ch]);
    }
    for (int i = tid; i < 256 * 12; i += 512) {
        int row = i / 12, ch = (i - row * 12) * 8;
        gload_lds16(aWt + (size_t)row * 96 + ch, &Bs[row][ch]);
    }
    __syncthreads();

    f32x4 acc[4][4];
    #pragma unroll
    for (int m = 0; m < 4; ++m)
        #pragma unroll
        for (int n = 0; n < 4; ++n) { f32x4 z = {0.f,0.f,0.f,0.f}; acc[m][n] = z; }

    #pragma unroll
    for (int h = 0; h < 3; ++h) {
        bf16x8 af[4], bf[4];
        #pragma unroll
        for (int m = 0; m < 4; ++m)
            af[m] = *reinterpret_cast<const bf16x8*>(&As[wr * 64 + m * 16 + lr][h * 32 + lq * 8]);
        #pragma unroll
        for (int n = 0; n < 4; ++n)
            bf[n] = *reinterpret_cast<const bf16x8*>(&Bs[wc * 64 + n * 16 + lr][h * 32 + lq * 8]);
        #pragma unroll
        for (int m = 0; m < 4; ++m)
            #pragma unroll
            for (int n = 0; n < 4; ++n)
                acc[m][n] = __builtin_amdgcn_mfma_f32_16x16x32_bf16(af[m], bf[n], acc[m][n], 0, 0, 0);
    }
    __syncthreads();

    // LDS-staged coalesced epilogue
    unsigned short* stg = shmem;
    #pragma unroll
    for (int half = 0; half < 2; ++half) {
        if (wr == half) {
            #pragma unroll
            for (int m = 0; m < 4; ++m)
                #pragma unroll
                for (int n = 0; n < 4; ++n) {
                    const int cs = (wc * 64 + n * 16 + lr) ^ (lq << 4);
                    #pragma unroll
                    for (int j = 0; j < 4; ++j)
                        stg[(m * 16 + lq * 4 + j) * 256 + cs] = f2bf(acc[m][n][j]);
                }
        }
        __syncthreads();
        const int rbase = m0 + half * 64;
        #pragma unroll
        for (int t = 0; t < 4; ++t) {
            int tt = tid + t * 512;
            int rl = tt >> 5, ch = tt & 31;
            int chs = ch ^ (((rl >> 2) & 3) << 1);
            us8 pv = *(const us8*)&stg[rl * 256 + chs * 8];
            ((us8*)x)[(size_t)(rbase + rl) * 32 + ch] = pv;
        }
        __syncthreads();
    }
}

// ---------------- CSR build ----------------
__global__ __launch_bounds__(256) void hist_kernel(const int* __restrict__ ei, int* __restrict__ counts) {
    int e = blockIdx.x * 256 + threadIdx.x;
    if (e < NEDGE) atomicAdd(&counts[ei[NEDGE + e]], 1);
}

__global__ __launch_bounds__(256) void scan1(const int* __restrict__ counts, int* __restrict__ blockSums) {
    int t = threadIdx.x;
    int base = blockIdx.x * 1024 + t * 4;
    int s = 0;
    #pragma unroll
    for (int i = 0; i < 4; ++i) { int idx = base + i; if (idx < NNODE) s += counts[idx]; }
    __shared__ int red[256];
    red[t] = s; __syncthreads();
    for (int d = 128; d; d >>= 1) { if (t < d) red[t] += red[t + d]; __syncthreads(); }
    if (t == 0) blockSums[blockIdx.x] = red[0];
}

__global__ __launch_bounds__(64) void scan2(int* __restrict__ blockSums) {
    int t = threadIdx.x;
    int v = (t < NCHUNK) ? blockSums[t] : 0;
    int orig = v;
    #pragma unroll
    for (int d = 1; d < 64; d <<= 1) {
        int o = __shfl_up(v, d);
        if (t >= d) v += o;
    }
    if (t < NCHUNK) blockSums[t] = v - orig;   // exclusive
}

__global__ __launch_bounds__(256) void scan3(const int* __restrict__ counts, const int* __restrict__ blockSums,
                                             int* __restrict__ offsets, int* __restrict__ cursor) {
    int t = threadIdx.x;
    int base = blockIdx.x * 1024 + t * 4;
    int c[4]; int s = 0;
    #pragma unroll
    for (int i = 0; i < 4; ++i) { int idx = base + i; c[i] = (idx < NNODE) ? counts[idx] : 0; s += c[i]; }
    __shared__ int lds[256];
    lds[t] = s; __syncthreads();
    for (int d = 1; d < 256; d <<= 1) {
        int v = (t >= d) ? lds[t - d] : 0;
        __syncthreads();
        lds[t] += v;
        __syncthreads();
    }
    int off = blockSums[blockIdx.x] + lds[t] - s;
    #pragma unroll
    for (int i = 0; i < 4; ++i) {
        int idx = base + i;
        if (idx < NNODE) { offsets[idx] = off; cursor[idx] = off; off += c[i]; }
    }
}

__global__ __launch_bounds__(256) void scatter_kernel(const int* __restrict__ ei, const float* __restrict__ aw,
                                                      int* __restrict__ cursor,
                                                      int* __restrict__ srow, float* __restrict__ sw) {
    int e = blockIdx.x * 256 + threadIdx.x;
    if (e < NEDGE) {
        int c = ei[NEDGE + e];
        int pos = atomicAdd(&cursor[c], 1);
        srow[pos] = ei[e];
        sw[pos] = aw[e];
    }
}

// ---------------- merged P/Q GEMM: BM=64, BN=256, 256 thr, 40 KB LDS ----------------
// 4 blocks/CU, grid = 118 supers x 16 (8 M-blocks x {P,Q}); twins same XCD.
// Full-N tile keeps the in-place state update race-free (block owns its 64 rows).
// P-half: C = [x|P]@wc1^T -> P = C, PX = C + x.  Q-half: C = [x|Qv]@wc2^T -> Qv = C + cq.
__global__ __launch_bounds__(256) void gemm_pq(const unsigned short* __restrict__ X,
                                               const unsigned short* __restrict__ Pst,
                                               const unsigned short* __restrict__ Qst,
                                               const unsigned short* __restrict__ B1,
                                               const unsigned short* __restrict__ B2,
                                               unsigned short* __restrict__ Pout,
                                               unsigned short* __restrict__ PXout,
                                               unsigned short* __restrict__ Qout,
                                               const float* __restrict__ cq,
                                               int Ktot) {
    __shared__ unsigned short shmem[64 * 64 + 256 * 64];   // A 8KB + B 32KB
    const int NMB = MPAD / 64;          // 938
    const int s = blockIdx.x >> 4;
    const int r = blockIdx.x & 15;
    const int mb = s * 8 + (r & 7);
    if (mb >= NMB) return;
    const int sel = r >> 3;
    const int m0 = mb * 64;

    const unsigned short* A1 = sel ? Qst : Pst;
    const unsigned short* Bt = sel ? B2 : B1;

    const int tid = threadIdx.x;
    const int lane = tid & 63, wid = tid >> 6;   // wid = wave's 64-col group
    const int lr = lane & 15, lq = lane >> 4;
    const int srow = tid >> 3;     // 0..31
    const int jphys = tid & 7;

    unsigned short* As = shmem;             // [64][64]
    unsigned short* Bs = shmem + 64 * 64;   // [256][64]

    f32x4 acc[4][4];
    #pragma unroll
    for (int m = 0; m < 4; ++m)
        #pragma unroll
        for (int n = 0; n < 4; ++n) { f32x4 z = {0.f,0.f,0.f,0.f}; acc[m][n] = z; }

    const int nk = Ktot >> 6;
    for (int kt = 0; kt < nk; ++kt) {
        const int k0 = kt << 6;
        const unsigned short* Ap; int ka;
        if (k0 < 256) { Ap = X; ka = k0; } else { Ap = A1; ka = k0 - 256; }
        #pragma unroll
        for (int p = 0; p < 2; ++p) {
            int row = p * 32 + srow;
            int jl = jphys ^ (row & 7);
            gload_lds16(Ap + (size_t)(m0 + row) * DD + ka + jl * 8, As + row * 64 + jphys * 8);
        }
        #pragma unroll
        for (int p = 0; p < 8; ++p) {
            int row = p * 32 + srow;
            int jl = jphys ^ (row & 7);
            gload_lds16(Bt + (size_t)row * 512 + k0 + jl * 8, Bs + row * 64 + jphys * 8);
        }
        __syncthreads();
        #pragma unroll
        for (int h = 0; h < 2; ++h) {
            const int jp = (((h * 4 + lq) ^ (lr & 7)) << 3);
            bf16x8 af[4], bfr[4];
            #pragma unroll
            for (int m = 0; m < 4; ++m)
                af[m] = *reinterpret_cast<const bf16x8*>(As + (m * 16 + lr) * 64 + jp);
            #pragma unroll
            for (int n = 0; n < 4; ++n)
                bfr[n] = *reinterpret_cast<const bf16x8*>(Bs + (wid * 64 + n * 16 + lr) * 64 + jp);
            #pragma unroll
            for (int m = 0; m < 4; ++m)
                #pragma unroll
                for (int n = 0; n < 4; ++n)
                    acc[m][n] = __builtin_amdgcn_mfma_f32_16x16x32_bf16(af[m], bfr[n], acc[m][n], 0, 0, 0);
        }
        __syncthreads();
    }

    // ---- LDS-staged coalesced epilogue (stg = 64x256 = 32 KB) ----
    float cqv[4];
    if (sel) {
        #pragma unroll
        for (int n = 0; n < 4; ++n) cqv[n] = cq[wid * 64 + n * 16 + lr];
    }
    unsigned short* stg = shmem;
    #pragma unroll
    for (int m = 0; m < 4; ++m)
        #pragma unroll
        for (int n = 0; n < 4; ++n) {
            const int cs = (wid * 64 + n * 16 + lr) ^ (lq << 4);
            #pragma unroll
            for (int j = 0; j < 4; ++j) {
                float v = acc[m][n][j];
                if (sel) v += cqv[n];
                stg[(m * 16 + lq * 4 + j) * 256 + cs] = f2bf(v);
            }
        }
    __syncthreads();
    #pragma unroll
    for (int t = 0; t < 8; ++t) {
        int tt = tid + t * 256;
        int rl = tt >> 5, ch = tt & 31;
        int chs = ch ^ (((rl >> 2) & 3) << 1);
        us8 pv = *(const us8*)&stg[rl * 256 + chs * 8];
        size_t gidx = (size_t)(m0 + rl) * 32 + ch;
        if (sel == 0) {
            us8 xv = ((const us8*)X)[gidx];
            us8 o;
            #pragma unroll
            for (int c = 0; c < 8; ++c) o[c] = f2bf(bf2f(pv[c]) + bf2f(xv[c]));
            ((us8*)Pout)[gidx] = pv;
            ((us8*)PXout)[gidx] = o;
        } else {
            ((us8*)Qout)[gidx] = pv;
        }
    }
}

// ---------------- BN GEMM: BM=64 x = relu((aggB @ nnt^T)*scale+shift) ----------------
__global__ __launch_bounds__(256) void gemm_bn(const unsigned short* __restrict__ A,
                                               const unsigned short* __restrict__ Bt,
                                               unsigned short* __restrict__ Cout,
                                               const float* __restrict__ scale,
                                               const float* __restrict__ shift) {
    __shared__ unsigned short shmem[64 * 64 + 256 * 64];
    const int m0 = blockIdx.x * 64;
    const int tid = threadIdx.x;
    const int lane = tid & 63, wid = tid >> 6;
    const int lr = lane & 15, lq = lane >> 4;
    const int srow = tid >> 3;
    const int jphys = tid & 7;

    unsigned short* As = shmem;
    unsigned short* Bs = shmem + 64 * 64;

    f32x4 acc[4][4];
    #pragma unroll
    for (int m = 0; m < 4; ++m)
        #pragma unroll
        for (int n = 0; n < 4; ++n) { f32x4 z = {0.f,0.f,0.f,0.f}; acc[m][n] = z; }

    for (int kt = 0; kt < 4; ++kt) {
        const int k0 = kt << 6;
        #pragma unroll
        for (int p = 0; p < 2; ++p) {
            int row = p * 32 + srow;
            int jl = jphys ^ (row & 7);
            gload_lds16(A + (size_t)(m0 + row) * DD + k0 + jl * 8, As + row * 64 + jphys * 8);
        }
        #pragma unroll
        for (int p = 0; p < 8; ++p) {
            int row = p * 32 + srow;
            int jl = jphys ^ (row & 7);
            gload_lds16(Bt + (size_t)row * DD + k0 + jl * 8, Bs + row * 64 + jphys * 8);
        }
        __syncthreads();
        #pragma unroll
        for (int h = 0; h < 2; ++h) {
            const int jp = (((h * 4 + lq) ^ (lr & 7)) << 3);
            bf16x8 af[4], bfr[4];
            #pragma unroll
            for (int m = 0; m < 4; ++m)
                af[m] = *reinterpret_cast<const bf16x8*>(As + (m * 16 + lr) * 64 + jp);
            #pragma unroll
            for (int n = 0; n < 4; ++n)
                bfr[n] = *reinterpret_cast<const bf16x8*>(Bs + (wid * 64 + n * 16 + lr) * 64 + jp);
            #pragma unroll
            for (int m = 0; m < 4; ++m)
                #pragma unroll
                for (int n = 0; n < 4; ++n)
                    acc[m][n] = __builtin_amdgcn_mfma_f32_16x16x32_bf16(af[m], bfr[n], acc[m][n], 0, 0, 0);
        }
        __syncthreads();
    }

    float scl[4], shf[4];
    #pragma unroll
    for (int n = 0; n < 4; ++n) {
        int c = wid * 64 + n * 16 + lr;
        scl[n] = scale[c]; shf[n] = shift[c];
    }
    unsigned short* stg = shmem;
    #pragma unroll
    for (int m = 0; m < 4; ++m)
        #pragma unroll
        for (int n = 0; n < 4; ++n) {
            const int cs = (wid * 64 + n * 16 + lr) ^ (lq << 4);
            #pragma unroll
            for (int j = 0; j < 4; ++j) {
                float y = fmaxf(acc[m][n][j] * scl[n] + shf[n], 0.f);
                stg[(m * 16 + lq * 4 + j) * 256 + cs] = f2bf(y);
            }
        }
    __syncthreads();
    #pragma unroll
    for (int t = 0; t < 8; ++t) {
        int tt = tid + t * 256;
        int rl = tt >> 5, ch = tt & 31;
        int chs = ch ^ (((rl >> 2) & 3) << 1);
        us8 pv = *(const us8*)&stg[rl * 256 + chs * 8];
        ((us8*)Cout)[(size_t)(m0 + rl) * 32 + ch] = pv;
    }
}

// ---------------- edge pass (CSR gather, single-gather): one wave per node ----------------
// aggB[n] = x[n] + sum_{e: col(e)=n} relu( PX[r] + Qv[n] + w*u )
__global__ __launch_bounds__(256) void edge_csr(const int* __restrict__ offsets, const int* __restrict__ counts,
                                                const int* __restrict__ srow, const float* __restrict__ sw,
                                                const unsigned short* __restrict__ X,
                                                const unsigned short* __restrict__ PX,
                                                const unsigned short* __restrict__ Qv,
                                                const float* __restrict__ u,
                                                unsigned short* __restrict__ aggB) {
    const int lane = threadIdx.x & 63, wid = threadIdx.x >> 6;
    const int n = blockIdx.x * 4 + wid;
    if (n >= NNODE) return;
    const int start = offsets[n];
    const int deg = counts[n];
    const int sub = lane & 31, h = lane >> 5;

    const us8* PX8 = (const us8*)PX;

    float4 u0 = ((const float4*)u)[sub * 2], u1 = ((const float4*)u)[sub * 2 + 1];
    float uu[8] = {u0.x, u0.y, u0.z, u0.w, u1.x, u1.y, u1.z, u1.w};

    us8 qv = ((const us8*)Qv)[(size_t)n * 32 + sub];
    float qb[8];
    #pragma unroll
    for (int c = 0; c < 8; ++c) qb[c] = bf2f(qv[c]);

    float a[8];
    us8 xv = ((const us8*)X)[(size_t)n * 32 + sub];
    #pragma unroll
    for (int c = 0; c < 8; ++c) a[c] = (h == 0) ? bf2f(xv[c]) : 0.f;

    for (int b0 = 0; b0 < deg; b0 += 64) {
        int m = deg - b0; if (m > 64) m = 64;
        int myr = 0; float myw = 0.f;
        if (lane < m) { myr = srow[start + b0 + lane]; myw = sw[start + b0 + lane]; }
        int iters = (m + 1) >> 1;
        for (int j = 0; j < iters; ++j) {
            int el = 2 * j + h;
            int r = __shfl(myr, el);
            float w = __shfl(myw, el);
            if (el < m) {
                us8 p2 = PX8[(size_t)r * 32 + sub];
                #pragma unroll
                for (int c = 0; c < 8; ++c)
                    a[c] += fmaxf(bf2f(p2[c]) + qb[c] + w * uu[c], 0.f);
            }
        }
    }
    #pragma unroll
    for (int c = 0; c < 8; ++c) a[c] += __shfl_xor(a[c], 32);
    if (h == 0) {
        us8 o;
        #pragma unroll
        for (int c = 0; c < 8; ++c) o[c] = f2bf(a[c]);
        ((us8*)aggB)[(size_t)n * 32 + sub] = o;
    }
}

// ---------------- pooling: pooled[batch[n]] += x[n], batch sorted ----------------
__global__ __launch_bounds__(256) void pool_kernel(const unsigned short* __restrict__ x,
                                                   const int* __restrict__ batch,
                                                   float* __restrict__ pooled) {
    const int lane = threadIdx.x & 63, wid = threadIdx.x >> 6;
    const int base = (blockIdx.x * 4 + wid) * 8;
    float4 acc = make_float4(0.f, 0.f, 0.f, 0.f);
    int gcur = -1;
    for (int i = 0; i < 8; ++i) {
        int n = base + i;
        if (n >= NNODE) break;
        int g = batch[n];
        if (g != gcur) {
            if (gcur >= 0) {
                float* pp = pooled + (size_t)gcur * DD + lane * 4;
                unsafeAtomicAdd(pp + 0, acc.x);
                unsafeAtomicAdd(pp + 1, acc.y);
                unsafeAtomicAdd(pp + 2, acc.z);
                unsafeAtomicAdd(pp + 3, acc.w);
            }
            gcur = g;
            acc = make_float4(0.f, 0.f, 0.f, 0.f);
        }
        ushort4 xv = ((const ushort4*)x)[(size_t)n * 64 + lane];
        acc.x += bf2f(xv.x); acc.y += bf2f(xv.y);
        acc.z += bf2f(xv.z); acc.w += bf2f(xv.w);
    }
    if (gcur >= 0) {
        float* pp = pooled + (size_t)gcur * DD + lane * 4;
        unsafeAtomicAdd(pp + 0, acc.x);
        unsafeAtomicAdd(pp + 1, acc.y);
        unsafeAtomicAdd(pp + 2, acc.z);
        unsafeAtomicAdd(pp + 3, acc.w);
    }
}

// ---------------- out: d_out = pooled @ outW + outb ----------------
__global__ __launch_bounds__(64) void out_kernel(const float* __restrict__ pooled,
                                                 const float* __restrict__ outW,
                                                 const float* __restrict__ outb,
                                                 float* __restrict__ out) {
    const int g = blockIdx.x, lane = threadIdx.x;
    float4 p = ((const float4*)pooled)[g * 64 + lane];
    float s[6];
    #pragma unroll
    for (int j = 0; j < 6; ++j) {
        float a = p.x * outW[(lane * 4 + 0) * 6 + j] + p.y * outW[(lane * 4 + 1) * 6 + j] +
                  p.z * outW[(lane * 4 + 2) * 6 + j] + p.w * outW[(lane * 4 + 3) * 6 + j];
        #pragma unroll
        for (int off = 32; off; off >>= 1) a += __shfl_down(a, off);
        s[j] = a;
    }
    if (lane == 0) {
        #pragma unroll
        for (int j = 0; j < 6; ++j) out[g * 6 + j] = s[j] + outb[j];
    }
}

extern "C" void kernel_launch(void* const* d_in, const int* in_sizes, int n_in,
                              void* d_out, int out_size, void* d_ws, size_t ws_size,
                              hipStream_t stream) {
    const float* nf    = (const float*)d_in[0];
    const int*   ei    = (const int*)d_in[1];
    const float* aw    = (const float*)d_in[2];
    const int*   batch = (const int*)d_in[3];
    const float* aW    = (const float*)d_in[4];
    const float* ab    = (const float*)d_in[5];
    const float* eW    = (const float*)d_in[6];
    const float* eb    = (const float*)d_in[7];
    const float* mlpW  = (const float*)d_in[8];
    const float* mlpb  = (const float*)d_in[9];
    const float* nnW   = (const float*)d_in[10];
    const float* nnb   = (const float*)d_in[11];
    const float* bn_g  = (const float*)d_in[12];
    const float* bn_b  = (const float*)d_in[13];
    const float* bn_m  = (const float*)d_in[14];
    const float* bn_v  = (const float*)d_in[15];
    const float* outW  = (const float*)d_in[16];
    const float* outb  = (const float*)d_in[17];
    float* out = (float*)d_out;

    char* ws = (char*)d_ws;
    size_t off = 0;
    auto alloc = [&](size_t bytes) -> void* {
        void* p = ws + off;
        off += (bytes + 255) & ~(size_t)255;
        return p;
    };
    unsigned short* x    = (unsigned short*)alloc((size_t)MPAD * DD * 2);
    unsigned short* P    = (unsigned short*)alloc((size_t)MPAD * DD * 2);
    unsigned short* Qv   = (unsigned short*)alloc((size_t)MPAD * DD * 2);
    unsigned short* aggB = (unsigned short*)alloc((size_t)MPAD * DD * 2);
    // PX shares its region with nfb (nfb dead after xinit; PX written from layer 0 on)
    unsigned short* PX   = (unsigned short*)alloc((size_t)MPAD * DD * 2);
    unsigned short* nfb  = PX;   // MPAD*96*2 < MPAD*DD*2, alias is safe
    unsigned short* wc1  = (unsigned short*)alloc(256 * 512 * 2);
    unsigned short* wc2  = (unsigned short*)alloc(256 * 512 * 2);
    unsigned short* nnt  = (unsigned short*)alloc(256 * 256 * 2);
    unsigned short* aWt  = (unsigned short*)alloc(256 * 96 * 2);
    float* u_all = (float*)alloc(4 * DD * 4);
    float* v_all = (float*)alloc(4 * DD * 4);
    float* scale = (float*)alloc(DD * 4);
    float* shift = (float*)alloc(DD * 4);
    float* pooled = (float*)alloc((size_t)NGRAPH * DD * 4);
    int* counts  = (int*)alloc((size_t)NNODE * 4);
    int* offsets = (int*)alloc((size_t)NNODE * 4);
    int* cursor  = (int*)alloc((size_t)NNODE * 4);
    int* blockSums = (int*)alloc(NCHUNK * 4);
    int* srowB   = (int*)alloc((size_t)NEDGE * 4);
    float* swB   = (float*)alloc((size_t)NEDGE * 4);
    (void)ws_size; (void)in_sizes; (void)n_in; (void)out_size;

    // one-time prep
    prep_weights<<<512, 256, 0, stream>>>(mlpW, nnW, aW, ab, wc1, wc2, nnt, aWt);
    prep_uv<<<1, 256, 0, stream>>>(eW, eb, mlpW, mlpb, nnb, bn_g, bn_b, bn_m, bn_v,
                                   u_all, v_all, scale, shift);
    nfb_prep<<<(MPAD * 96 + 255) / 256, 256, 0, stream>>>(nf, nfb);
    xinit_gemm<<<MPAD / 128, 512, 0, stream>>>(nfb, aWt, x);

    // CSR build (once; shared by all 4 layers)
    hipMemsetAsync(counts, 0, (size_t)NNODE * 4, stream);
    hist_kernel<<<(NEDGE + 255) / 256, 256, 0, stream>>>(ei, counts);
    scan1<<<NCHUNK, 256, 0, stream>>>(counts, blockSums);
    scan2<<<1, 64, 0, stream>>>(blockSums);
    scan3<<<NCHUNK, 256, 0, stream>>>(counts, blockSums, offsets, cursor);
    scatter_kernel<<<(NEDGE + 255) / 256, 256, 0, stream>>>(ei, aw, cursor, srowB, swB);

    const int nsup = (MPAD / 64 + 7) / 8;   // 118
    for (int k = 0; k < 4; ++k) {
        gemm_pq<<<nsup * 16, 256, 0, stream>>>(x, P, Qv, wc1, wc2, P, PX, Qv,
                                               k == 0 ? v_all : mlpb, k ? 512 : 256);
        edge_csr<<<(NNODE + 3) / 4, 256, 0, stream>>>(offsets, counts, srowB, swB, x, PX, Qv,
                                                      u_all + k * DD, aggB);
        gemm_bn<<<MPAD / 64, 256, 0, stream>>>(aggB, nnt, x, scale, shift);
    }

    hipMemsetAsync(pooled, 0, (size_t)NGRAPH * DD * 4, stream);
    pool_kernel<<<(NNODE + 31) / 32, 256, 0, stream>>>(x, batch, pooled);
    out_kernel<<<NGRAPH, 64, 0, stream>>>(pooled, outW, outb, out);
}

// Round 10
// 505.255 us; speedup vs baseline: 1.1646x; 1.0723x over previous
//
#include <hip/hip_runtime.h>
#include <stdint.h>

#define DD 256
#define NNODE 60000
#define MPAD 60032            // 469 * 128
#define NEDGE 200000
#define NGRAPH 1500
#define NCHUNK 59             // ceil(60000/1024)

typedef __bf16 bf16x8 __attribute__((ext_vector_type(8)));
typedef float f32x4 __attribute__((ext_vector_type(4)));
typedef unsigned short us8 __attribute__((ext_vector_type(8)));

__device__ __forceinline__ unsigned short f2bf(float f) {
    union { float f; unsigned int u; } v; v.f = f;
    unsigned int r = v.u + 0x7FFFu + ((v.u >> 16) & 1u);
    return (unsigned short)(r >> 16);
}
__device__ __forceinline__ float bf2f(unsigned short h) {
    union { unsigned int u; float f; } v; v.u = ((unsigned int)h) << 16;
    return v.f;
}
__device__ __forceinline__ void gload_lds16(const void* g, void* l) {
    __builtin_amdgcn_global_load_lds((const __attribute__((address_space(1))) void*)g,
                                     (__attribute__((address_space(3))) void*)l, 16, 0, 0);
}

// ---------------- weight prep: transposed bf16 weights ----------------
__global__ __launch_bounds__(256) void prep_weights(const float* __restrict__ mlpW,
                                                    const float* __restrict__ nnW,
                                                    const float* __restrict__ aW,
                                                    const float* __restrict__ ab,
                                                    unsigned short* __restrict__ wc1,
                                                    unsigned short* __restrict__ wc2,
                                                    unsigned short* __restrict__ nnt,
                                                    unsigned short* __restrict__ aWt) {
    int idx = blockIdx.x * 256 + threadIdx.x;
    if (idx < 256 * 512) {
        int n = idx >> 9, k = idx & 511;
        float v1 = (k < 256) ? mlpW[k * DD + n] : mlpW[(k + 256) * DD + n];
        wc1[idx] = f2bf(v1);
        wc2[idx] = f2bf(mlpW[(k + 256) * DD + n]);
    }
    if (idx < 256 * 256) {
        int n = idx >> 8, k = idx & 255;
        nnt[idx] = f2bf(nnW[k * DD + n]);
    }
    if (idx < 256 * 96) {
        int n = idx / 96, k = idx - n * 96;
        float v = (k < 92) ? aW[k * DD + n] : (k == 92 ? ab[n] : 0.0f);
        aWt[idx] = f2bf(v);
    }
}

// ---------------- u/v chains + BN fold ----------------
__global__ __launch_bounds__(256) void prep_uv(const float* __restrict__ eW, const float* __restrict__ eb,
                                               const float* __restrict__ mlpW, const float* __restrict__ mlpb,
                                               const float* __restrict__ nnb,
                                               const float* __restrict__ bn_g, const float* __restrict__ bn_b,
                                               const float* __restrict__ bn_m, const float* __restrict__ bn_v,
                                               float* __restrict__ u_all, float* __restrict__ v_all,
                                               float* __restrict__ scale, float* __restrict__ shift) {
    __shared__ float uc[DD], vc[DD];
    int d = threadIdx.x;
    uc[d] = eW[d];
    vc[d] = eb[d];
    float sc = bn_g[d] * rsqrtf(bn_v[d] + 1e-5f);
    scale[d] = sc;
    shift[d] = (nnb[d] - bn_m[d]) * sc + bn_b[d];
    __syncthreads();
    const float* W3 = mlpW + 2 * DD * DD;
    for (int it = 0; it < 4; ++it) {
        float su = 0.f, sv = 0.f;
        for (int k = 0; k < DD; ++k) {
            float w = W3[k * DD + d];
            su += uc[k] * w;
            sv += vc[k] * w;
        }
        sv += mlpb[d];
        u_all[it * DD + d] = su;
        v_all[it * DD + d] = sv;
        __syncthreads();
        uc[d] = su; vc[d] = sv;
        __syncthreads();
    }
}

// ---------------- nf -> bf16 padded [MPAD][96] with bias column ----------------
__global__ __launch_bounds__(256) void nfb_prep(const float* __restrict__ nf, unsigned short* __restrict__ nfb) {
    int idx = blockIdx.x * 256 + threadIdx.x;
    if (idx >= MPAD * 96) return;
    int r = idx / 96, c = idx - r * 96;
    float v;
    if (r < NNODE && c < 92) v = nf[(size_t)r * 92 + c];
    else v = (c == 92) ? 1.0f : 0.0f;
    nfb[idx] = f2bf(v);
}

// ---------------- xinit GEMM: x[M][256] = nfb[M][96] @ aWt^T, single-stage ----------------
__global__ __launch_bounds__(512) void xinit_gemm(const unsigned short* __restrict__ nfb,
                                                  const unsigned short* __restrict__ aWt,
                                                  unsigned short* __restrict__ x) {
    __shared__ unsigned short shmem[(128 + 256) * 96];
    unsigned short (*As)[96] = (unsigned short(*)[96])shmem;
    unsigned short (*Bs)[96] = (unsigned short(*)[96])(shmem + 128 * 96);
    const int tid = threadIdx.x;
    const int lane = tid & 63, wid = tid >> 6;
    const int wr = wid >> 2, wc = wid & 3;
    const int m0 = blockIdx.x * 128;
    const int lr = lane & 15, lq = lane >> 4;

    for (int i = tid; i < 128 * 12; i += 512) {
        int row = i / 12, ch = (i - row * 12) * 8;
        gload_lds16(nfb + (size_t)(m0 + row) * 96 + ch, &As[row][ch]);
    }
    for (int i = tid; i < 256 * 12; i += 512) {
        int row = i / 12, ch = (i - row * 12) * 8;
        gload_lds16(aWt + (size_t)row * 96 + ch, &Bs[row][ch]);
    }
    __syncthreads();

    f32x4 acc[4][4];
    #pragma unroll
    for (int m = 0; m < 4; ++m)
        #pragma unroll
        for (int n = 0; n < 4; ++n) { f32x4 z = {0.f,0.f,0.f,0.f}; acc[m][n] = z; }

    #pragma unroll
    for (int h = 0; h < 3; ++h) {
        bf16x8 af[4], bf[4];
        #pragma unroll
        for (int m = 0; m < 4; ++m)
            af[m] = *reinterpret_cast<const bf16x8*>(&As[wr * 64 + m * 16 + lr][h * 32 + lq * 8]);
        #pragma unroll
        for (int n = 0; n < 4; ++n)
            bf[n] = *reinterpret_cast<const bf16x8*>(&Bs[wc * 64 + n * 16 + lr][h * 32 + lq * 8]);
        #pragma unroll
        for (int m = 0; m < 4; ++m)
            #pragma unroll
            for (int n = 0; n < 4; ++n)
                acc[m][n] = __builtin_amdgcn_mfma_f32_16x16x32_bf16(af[m], bf[n], acc[m][n], 0, 0, 0);
    }
    __syncthreads();

    // LDS-staged coalesced epilogue
    unsigned short* stg = shmem;
    #pragma unroll
    for (int half = 0; half < 2; ++half) {
        if (wr == half) {
            #pragma unroll
            for (int m = 0; m < 4; ++m)
                #pragma unroll
                for (int n = 0; n < 4; ++n) {
                    const int cs = (wc * 64 + n * 16 + lr) ^ (lq << 4);
                    #pragma unroll
                    for (int j = 0; j < 4; ++j)
                        stg[(m * 16 + lq * 4 + j) * 256 + cs] = f2bf(acc[m][n][j]);
                }
        }
        __syncthreads();
        const int rbase = m0 + half * 64;
        #pragma unroll
        for (int t = 0; t < 4; ++t) {
            int tt = tid + t * 512;
            int rl = tt >> 5, ch = tt & 31;
            int chs = ch ^ (((rl >> 2) & 3) << 1);
            us8 pv = *(const us8*)&stg[rl * 256 + chs * 8];
            ((us8*)x)[(size_t)(rbase + rl) * 32 + ch] = pv;
        }
        __syncthreads();
    }
}

// ---------------- CSR build ----------------
__global__ __launch_bounds__(256) void hist_kernel(const int* __restrict__ ei, int* __restrict__ counts) {
    int e = blockIdx.x * 256 + threadIdx.x;
    if (e < NEDGE) atomicAdd(&counts[ei[NEDGE + e]], 1);
}

__global__ __launch_bounds__(256) void scan1(const int* __restrict__ counts, int* __restrict__ blockSums) {
    int t = threadIdx.x;
    int base = blockIdx.x * 1024 + t * 4;
    int s = 0;
    #pragma unroll
    for (int i = 0; i < 4; ++i) { int idx = base + i; if (idx < NNODE) s += counts[idx]; }
    __shared__ int red[256];
    red[t] = s; __syncthreads();
    for (int d = 128; d; d >>= 1) { if (t < d) red[t] += red[t + d]; __syncthreads(); }
    if (t == 0) blockSums[blockIdx.x] = red[0];
}

__global__ __launch_bounds__(64) void scan2(int* __restrict__ blockSums) {
    int t = threadIdx.x;
    int v = (t < NCHUNK) ? blockSums[t] : 0;
    int orig = v;
    #pragma unroll
    for (int d = 1; d < 64; d <<= 1) {
        int o = __shfl_up(v, d);
        if (t >= d) v += o;
    }
    if (t < NCHUNK) blockSums[t] = v - orig;   // exclusive
}

__global__ __launch_bounds__(256) void scan3(const int* __restrict__ counts, const int* __restrict__ blockSums,
                                             int* __restrict__ offsets, int* __restrict__ cursor) {
    int t = threadIdx.x;
    int base = blockIdx.x * 1024 + t * 4;
    int c[4]; int s = 0;
    #pragma unroll
    for (int i = 0; i < 4; ++i) { int idx = base + i; c[i] = (idx < NNODE) ? counts[idx] : 0; s += c[i]; }
    __shared__ int lds[256];
    lds[t] = s; __syncthreads();
    for (int d = 1; d < 256; d <<= 1) {
        int v = (t >= d) ? lds[t - d] : 0;
        __syncthreads();
        lds[t] += v;
        __syncthreads();
    }
    int off = blockSums[blockIdx.x] + lds[t] - s;
    #pragma unroll
    for (int i = 0; i < 4; ++i) {
        int idx = base + i;
        if (idx < NNODE) { offsets[idx] = off; cursor[idx] = off; off += c[i]; }
    }
}

__global__ __launch_bounds__(256) void scatter_kernel(const int* __restrict__ ei, const float* __restrict__ aw,
                                                      int* __restrict__ cursor,
                                                      int* __restrict__ srow, float* __restrict__ sw) {
    int e = blockIdx.x * 256 + threadIdx.x;
    if (e < NEDGE) {
        int c = ei[NEDGE + e];
        int pos = atomicAdd(&cursor[c], 1);
        srow[pos] = ei[e];
        sw[pos] = aw[e];
    }
}

// ---------------- merged P/Q GEMM, swizzled LDS, 48 KB, LDS-staged epilogue ----------------
// Twin mapping: bids 16p+{0..7} = P-half, 16p+{8..15} = Q-half of the SAME 8
// M-blocks; twin XCD = sub%8 = mb%8, matching the gemm_bn producer of x.
__global__ __launch_bounds__(512) void gemm_pq(const unsigned short* __restrict__ X,
                                               const unsigned short* __restrict__ Pst,
                                               const unsigned short* __restrict__ Qst,
                                               const unsigned short* __restrict__ B1,
                                               const unsigned short* __restrict__ B2,
                                               unsigned short* __restrict__ Pout,
                                               unsigned short* __restrict__ PXout,
                                               unsigned short* __restrict__ Qout,
                                               const float* __restrict__ cq,
                                               int Ktot) {
    __shared__ unsigned short shmem[(128 + 256) * 64];
    unsigned short (*As)[64] = (unsigned short(*)[64])shmem;
    unsigned short (*Bs)[64] = (unsigned short(*)[64])(shmem + 128 * 64);
    const int b = blockIdx.x;
    const int pairb = b >> 4, jj = b & 15;
    const int sel = jj >> 3, sub = jj & 7;
    const int mb = pairb * 8 + sub;
    if (mb >= MPAD / 128) return;
    const int m0 = mb * 128;

    const unsigned short* A1 = sel ? Qst : Pst;
    const unsigned short* Bt = sel ? B2 : B1;

    const int tid = threadIdx.x;
    const int lane = tid & 63, wid = tid >> 6;
    const int wr = wid >> 2, wc = wid & 3;
    const int lr = lane & 15, lq = lane >> 4;
    const int srow = tid >> 3;
    const int jphys = tid & 7;
    const int jlog = jphys ^ (srow & 7);
    const int scol_g = jlog * 8;
    const int scol_l = jphys * 8;
    const int xorj = (lr & 7);

    f32x4 acc[4][4];
    #pragma unroll
    for (int m = 0; m < 4; ++m)
        #pragma unroll
        for (int n = 0; n < 4; ++n) { f32x4 z = {0.f,0.f,0.f,0.f}; acc[m][n] = z; }

    const int nk = Ktot >> 6;
    for (int kt = 0; kt < nk; ++kt) {
        const int k0 = kt << 6;
        const unsigned short* Ap; int ka;
        if (k0 < 256) { Ap = X; ka = k0; } else { Ap = A1; ka = k0 - 256; }
        #pragma unroll
        for (int p = 0; p < 2; ++p) {
            int row = p * 64 + srow;
            gload_lds16(Ap + (size_t)(m0 + row) * DD + ka + scol_g, &As[row][scol_l]);
        }
        #pragma unroll
        for (int p = 0; p < 4; ++p) {
            int row = p * 64 + srow;
            gload_lds16(Bt + (size_t)row * 512 + k0 + scol_g, &Bs[row][scol_l]);
        }
        __syncthreads();
        #pragma unroll
        for (int h = 0; h < 2; ++h) {
            const int jp = ((h * 4 + lq) ^ xorj) * 8;
            bf16x8 af[4], bfr[4];
            #pragma unroll
            for (int m = 0; m < 4; ++m)
                af[m] = *reinterpret_cast<const bf16x8*>(&As[wr * 64 + m * 16 + lr][jp]);
            #pragma unroll
            for (int n = 0; n < 4; ++n)
                bfr[n] = *reinterpret_cast<const bf16x8*>(&Bs[wc * 64 + n * 16 + lr][jp]);
            #pragma unroll
            for (int m = 0; m < 4; ++m)
                #pragma unroll
                for (int n = 0; n < 4; ++n)
                    acc[m][n] = __builtin_amdgcn_mfma_f32_16x16x32_bf16(af[m], bfr[n], acc[m][n], 0, 0, 0);
        }
        __syncthreads();
    }

    // ---- LDS-staged coalesced epilogue ----
    float cqv[4];
    if (sel) {
        #pragma unroll
        for (int n = 0; n < 4; ++n) cqv[n] = cq[wc * 64 + n * 16 + lr];
    }
    unsigned short* stg = shmem;
    #pragma unroll
    for (int half = 0; half < 2; ++half) {
        if (wr == half) {
            #pragma unroll
            for (int m = 0; m < 4; ++m)
                #pragma unroll
                for (int n = 0; n < 4; ++n) {
                    const int cs = (wc * 64 + n * 16 + lr) ^ (lq << 4);
                    #pragma unroll
                    for (int j = 0; j < 4; ++j) {
                        float v = acc[m][n][j];
                        if (sel) v += cqv[n];
                        stg[(m * 16 + lq * 4 + j) * 256 + cs] = f2bf(v);
                    }
                }
        }
        __syncthreads();
        const int rbase = m0 + half * 64;
        #pragma unroll
        for (int t = 0; t < 4; ++t) {
            int tt = tid + t * 512;
            int rl = tt >> 5, ch = tt & 31;
            int chs = ch ^ (((rl >> 2) & 3) << 1);
            us8 pv = *(const us8*)&stg[rl * 256 + chs * 8];
            size_t gidx = (size_t)(rbase + rl) * 32 + ch;
            if (sel == 0) {
                us8 xv = ((const us8*)X)[gidx];
                us8 o;
                #pragma unroll
                for (int c = 0; c < 8; ++c) o[c] = f2bf(bf2f(pv[c]) + bf2f(xv[c]));
                ((us8*)Pout)[gidx] = pv;
                ((us8*)PXout)[gidx] = o;
            } else {
                ((us8*)Qout)[gidx] = pv;
            }
        }
        __syncthreads();
    }
}

// ---------------- BN GEMM: x = relu((aggB @ nnt^T) * scale + shift), staged epilogue ----------------
__global__ __launch_bounds__(512) void gemm_bn(const unsigned short* __restrict__ A,
                                               const unsigned short* __restrict__ Bt,
                                               unsigned short* __restrict__ Cout,
                                               const float* __restrict__ scale,
                                               const float* __restrict__ shift) {
    __shared__ unsigned short shmem[(128 + 256) * 64];
    unsigned short (*As)[64] = (unsigned short(*)[64])shmem;
    unsigned short (*Bs)[64] = (unsigned short(*)[64])(shmem + 128 * 64);
    const int tid = threadIdx.x;
    const int lane = tid & 63, wid = tid >> 6;
    const int wr = wid >> 2, wc = wid & 3;
    const int m0 = blockIdx.x * 128;
    const int lr = lane & 15, lq = lane >> 4;
    const int srow = tid >> 3;
    const int jphys = tid & 7;
    const int jlog = jphys ^ (srow & 7);
    const int scol_g = jlog * 8;
    const int scol_l = jphys * 8;
    const int xorj = (lr & 7);

    f32x4 acc[4][4];
    #pragma unroll
    for (int m = 0; m < 4; ++m)
        #pragma unroll
        for (int n = 0; n < 4; ++n) { f32x4 z = {0.f,0.f,0.f,0.f}; acc[m][n] = z; }

    for (int kt = 0; kt < 4; ++kt) {
        const int k0 = kt << 6;
        #pragma unroll
        for (int p = 0; p < 2; ++p) {
            int row = p * 64 + srow;
            gload_lds16(A + (size_t)(m0 + row) * DD + k0 + scol_g, &As[row][scol_l]);
        }
        #pragma unroll
        for (int p = 0; p < 4; ++p) {
            int row = p * 64 + srow;
            gload_lds16(Bt + (size_t)row * DD + k0 + scol_g, &Bs[row][scol_l]);
        }
        __syncthreads();
        #pragma unroll
        for (int h = 0; h < 2; ++h) {
            const int jp = ((h * 4 + lq) ^ xorj) * 8;
            bf16x8 af[4], bfr[4];
            #pragma unroll
            for (int m = 0; m < 4; ++m)
                af[m] = *reinterpret_cast<const bf16x8*>(&As[wr * 64 + m * 16 + lr][jp]);
            #pragma unroll
            for (int n = 0; n < 4; ++n)
                bfr[n] = *reinterpret_cast<const bf16x8*>(&Bs[wc * 64 + n * 16 + lr][jp]);
            #pragma unroll
            for (int m = 0; m < 4; ++m)
                #pragma unroll
                for (int n = 0; n < 4; ++n)
                    acc[m][n] = __builtin_amdgcn_mfma_f32_16x16x32_bf16(af[m], bfr[n], acc[m][n], 0, 0, 0);
        }
        __syncthreads();
    }

    float scl[4], shf[4];
    #pragma unroll
    for (int n = 0; n < 4; ++n) {
        int c = wc * 64 + n * 16 + lr;
        scl[n] = scale[c]; shf[n] = shift[c];
    }
    unsigned short* stg = shmem;
    #pragma unroll
    for (int half = 0; half < 2; ++half) {
        if (wr == half) {
            #pragma unroll
            for (int m = 0; m < 4; ++m)
                #pragma unroll
                for (int n = 0; n < 4; ++n) {
                    const int cs = (wc * 64 + n * 16 + lr) ^ (lq << 4);
                    #pragma unroll
                    for (int j = 0; j < 4; ++j) {
                        float y = fmaxf(acc[m][n][j] * scl[n] + shf[n], 0.f);
                        stg[(m * 16 + lq * 4 + j) * 256 + cs] = f2bf(y);
                    }
                }
        }
        __syncthreads();
        const int rbase = m0 + half * 64;
        #pragma unroll
        for (int t = 0; t < 4; ++t) {
            int tt = tid + t * 512;
            int rl = tt >> 5, ch = tt & 31;
            int chs = ch ^ (((rl >> 2) & 3) << 1);
            us8 pv = *(const us8*)&stg[rl * 256 + chs * 8];
            ((us8*)Cout)[(size_t)(rbase + rl) * 32 + ch] = pv;
        }
        __syncthreads();
    }
}

// ---------------- edge pass (CSR gather, XCD-aligned): one wave per node ----------------
// Node-group g (4 nodes) is placed on XCD (g/32)%8 so that its x/Qv reads hit the
// L2 of the gemm_pq/gemm_bn block (mb = g/32, XCD mb%8) that produced those rows,
// and its aggB writes stay local for the consuming gemm_bn block.
// aggB[n] = x[n] + sum_{e: col(e)=n} relu( PX[r] + Qv[n] + w*u )
__global__ __launch_bounds__(256) void edge_csr(const int* __restrict__ offsets, const int* __restrict__ counts,
                                                const int* __restrict__ srow, const float* __restrict__ sw,
                                                const unsigned short* __restrict__ X,
                                                const unsigned short* __restrict__ PX,
                                                const unsigned short* __restrict__ Qv,
                                                const float* __restrict__ u,
                                                unsigned short* __restrict__ aggB) {
    const int lane = threadIdx.x & 63, wid = threadIdx.x >> 6;
    // XCD-aligned block->group mapping (assumes round-robin XCD = blockIdx%8)
    const int cls = blockIdx.x & 7;
    const int i = blockIdx.x >> 3;
    const int chunk = (i >> 5) * 8 + cls;        // 32 groups (=128 nodes) per chunk
    const int g = chunk * 32 + (i & 31);
    const int n = g * 4 + wid;
    if (n >= NNODE) return;
    const int start = offsets[n];
    const int deg = counts[n];
    const int sub = lane & 31, h = lane >> 5;

    const us8* PX8 = (const us8*)PX;

    float4 u0 = ((const float4*)u)[sub * 2], u1 = ((const float4*)u)[sub * 2 + 1];
    float uu[8] = {u0.x, u0.y, u0.z, u0.w, u1.x, u1.y, u1.z, u1.w};

    us8 qv = ((const us8*)Qv)[(size_t)n * 32 + sub];
    float qb[8];
    #pragma unroll
    for (int c = 0; c < 8; ++c) qb[c] = bf2f(qv[c]);

    float a[8];
    us8 xv = ((const us8*)X)[(size_t)n * 32 + sub];
    #pragma unroll
    for (int c = 0; c < 8; ++c) a[c] = (h == 0) ? bf2f(xv[c]) : 0.f;

    for (int b0 = 0; b0 < deg; b0 += 64) {
        int m = deg - b0; if (m > 64) m = 64;
        int myr = 0; float myw = 0.f;
        if (lane < m) { myr = srow[start + b0 + lane]; myw = sw[start + b0 + lane]; }
        int iters = (m + 1) >> 1;
        for (int j = 0; j < iters; ++j) {
            int el = 2 * j + h;
            int r = __shfl(myr, el);
            float w = __shfl(myw, el);
            if (el < m) {
                us8 p2 = PX8[(size_t)r * 32 + sub];
                #pragma unroll
                for (int c = 0; c < 8; ++c)
                    a[c] += fmaxf(bf2f(p2[c]) + qb[c] + w * uu[c], 0.f);
            }
        }
    }
    #pragma unroll
    for (int c = 0; c < 8; ++c) a[c] += __shfl_xor(a[c], 32);
    if (h == 0) {
        us8 o;
        #pragma unroll
        for (int c = 0; c < 8; ++c) o[c] = f2bf(a[c]);
        ((us8*)aggB)[(size_t)n * 32 + sub] = o;
    }
}

// ---------------- pooling: pooled[batch[n]] += x[n], batch sorted ----------------
__global__ __launch_bounds__(256) void pool_kernel(const unsigned short* __restrict__ x,
                                                   const int* __restrict__ batch,
                                                   float* __restrict__ pooled) {
    const int lane = threadIdx.x & 63, wid = threadIdx.x >> 6;
    const int base = (blockIdx.x * 4 + wid) * 8;
    float4 acc = make_float4(0.f, 0.f, 0.f, 0.f);
    int gcur = -1;
    for (int i = 0; i < 8; ++i) {
        int n = base + i;
        if (n >= NNODE) break;
        int g = batch[n];
        if (g != gcur) {
            if (gcur >= 0) {
                float* pp = pooled + (size_t)gcur * DD + lane * 4;
                unsafeAtomicAdd(pp + 0, acc.x);
                unsafeAtomicAdd(pp + 1, acc.y);
                unsafeAtomicAdd(pp + 2, acc.z);
                unsafeAtomicAdd(pp + 3, acc.w);
            }
            gcur = g;
            acc = make_float4(0.f, 0.f, 0.f, 0.f);
        }
        ushort4 xv = ((const ushort4*)x)[(size_t)n * 64 + lane];
        acc.x += bf2f(xv.x); acc.y += bf2f(xv.y);
        acc.z += bf2f(xv.z); acc.w += bf2f(xv.w);
    }
    if (gcur >= 0) {
        float* pp = pooled + (size_t)gcur * DD + lane * 4;
        unsafeAtomicAdd(pp + 0, acc.x);
        unsafeAtomicAdd(pp + 1, acc.y);
        unsafeAtomicAdd(pp + 2, acc.z);
        unsafeAtomicAdd(pp + 3, acc.w);
    }
}

// ---------------- out: d_out = pooled @ outW + outb ----------------
__global__ __launch_bounds__(64) void out_kernel(const float* __restrict__ pooled,
                                                 const float* __restrict__ outW,
                                                 const float* __restrict__ outb,
                                                 float* __restrict__ out) {
    const int g = blockIdx.x, lane = threadIdx.x;
    float4 p = ((const float4*)pooled)[g * 64 + lane];
    float s[6];
    #pragma unroll
    for (int j = 0; j < 6; ++j) {
        float a = p.x * outW[(lane * 4 + 0) * 6 + j] + p.y * outW[(lane * 4 + 1) * 6 + j] +
                  p.z * outW[(lane * 4 + 2) * 6 + j] + p.w * outW[(lane * 4 + 3) * 6 + j];
        #pragma unroll
        for (int off = 32; off; off >>= 1) a += __shfl_down(a, off);
        s[j] = a;
    }
    if (lane == 0) {
        #pragma unroll
        for (int j = 0; j < 6; ++j) out[g * 6 + j] = s[j] + outb[j];
    }
}

extern "C" void kernel_launch(void* const* d_in, const int* in_sizes, int n_in,
                              void* d_out, int out_size, void* d_ws, size_t ws_size,
                              hipStream_t stream) {
    const float* nf    = (const float*)d_in[0];
    const int*   ei    = (const int*)d_in[1];
    const float* aw    = (const float*)d_in[2];
    const int*   batch = (const int*)d_in[3];
    const float* aW    = (const float*)d_in[4];
    const float* ab    = (const float*)d_in[5];
    const float* eW    = (const float*)d_in[6];
    const float* eb    = (const float*)d_in[7];
    const float* mlpW  = (const float*)d_in[8];
    const float* mlpb  = (const float*)d_in[9];
    const float* nnW   = (const float*)d_in[10];
    const float* nnb   = (const float*)d_in[11];
    const float* bn_g  = (const float*)d_in[12];
    const float* bn_b  = (const float*)d_in[13];
    const float* bn_m  = (const float*)d_in[14];
    const float* bn_v  = (const float*)d_in[15];
    const float* outW  = (const float*)d_in[16];
    const float* outb  = (const float*)d_in[17];
    float* out = (float*)d_out;

    char* ws = (char*)d_ws;
    size_t off = 0;
    auto alloc = [&](size_t bytes) -> void* {
        void* p = ws + off;
        off += (bytes + 255) & ~(size_t)255;
        return p;
    };
    unsigned short* x    = (unsigned short*)alloc((size_t)MPAD * DD * 2);
    unsigned short* P    = (unsigned short*)alloc((size_t)MPAD * DD * 2);
    unsigned short* Qv   = (unsigned short*)alloc((size_t)MPAD * DD * 2);
    unsigned short* aggB = (unsigned short*)alloc((size_t)MPAD * DD * 2);
    // PX shares its region with nfb (nfb dead after xinit; PX written from layer 0 on)
    unsigned short* PX   = (unsigned short*)alloc((size_t)MPAD * DD * 2);
    unsigned short* nfb  = PX;   // MPAD*96*2 < MPAD*DD*2, alias is safe
    unsigned short* wc1  = (unsigned short*)alloc(256 * 512 * 2);
    unsigned short* wc2  = (unsigned short*)alloc(256 * 512 * 2);
    unsigned short* nnt  = (unsigned short*)alloc(256 * 256 * 2);
    unsigned short* aWt  = (unsigned short*)alloc(256 * 96 * 2);
    float* u_all = (float*)alloc(4 * DD * 4);
    float* v_all = (float*)alloc(4 * DD * 4);
    float* scale = (float*)alloc(DD * 4);
    float* shift = (float*)alloc(DD * 4);
    float* pooled = (float*)alloc((size_t)NGRAPH * DD * 4);
    int* counts  = (int*)alloc((size_t)NNODE * 4);
    int* offsets = (int*)alloc((size_t)NNODE * 4);
    int* cursor  = (int*)alloc((size_t)NNODE * 4);
    int* blockSums = (int*)alloc(NCHUNK * 4);
    int* srowB   = (int*)alloc((size_t)NEDGE * 4);
    float* swB   = (float*)alloc((size_t)NEDGE * 4);
    (void)ws_size; (void)in_sizes; (void)n_in; (void)out_size;

    // one-time prep
    prep_weights<<<512, 256, 0, stream>>>(mlpW, nnW, aW, ab, wc1, wc2, nnt, aWt);
    prep_uv<<<1, 256, 0, stream>>>(eW, eb, mlpW, mlpb, nnb, bn_g, bn_b, bn_m, bn_v,
                                   u_all, v_all, scale, shift);
    nfb_prep<<<(MPAD * 96 + 255) / 256, 256, 0, stream>>>(nf, nfb);
    xinit_gemm<<<MPAD / 128, 512, 0, stream>>>(nfb, aWt, x);

    // CSR build (once; shared by all 4 layers)
    hipMemsetAsync(counts, 0, (size_t)NNODE * 4, stream);
    hist_kernel<<<(NEDGE + 255) / 256, 256, 0, stream>>>(ei, counts);
    scan1<<<NCHUNK, 256, 0, stream>>>(counts, blockSums);
    scan2<<<1, 64, 0, stream>>>(blockSums);
    scan3<<<NCHUNK, 256, 0, stream>>>(counts, blockSums, offsets, cursor);
    scatter_kernel<<<(NEDGE + 255) / 256, 256, 0, stream>>>(ei, aw, cursor, srowB, swB);

    const int npairs = (MPAD / 128 + 7) / 8;   // 59
    // edge grid: 8 XCD classes x 59 chunks-per-class x 32 groups = 15104 blocks
    const int edge_blocks = 8 * 59 * 32;
    for (int k = 0; k < 4; ++k) {
        gemm_pq<<<npairs * 16, 512, 0, stream>>>(x, P, Qv, wc1, wc2, P, PX, Qv,
                                                 k == 0 ? v_all : mlpb, k ? 512 : 256);
        edge_csr<<<edge_blocks, 256, 0, stream>>>(offsets, counts, srowB, swB, x, PX, Qv,
                                                  u_all + k * DD, aggB);
        gemm_bn<<<MPAD / 128, 512, 0, stream>>>(aggB, nnt, x, scale, shift);
    }

    hipMemsetAsync(pooled, 0, (size_t)NGRAPH * DD * 4, stream);
    pool_kernel<<<(NNODE + 31) / 32, 256, 0, stream>>>(x, batch, pooled);
    out_kernel<<<NGRAPH, 64, 0, stream>>>(pooled, outW, outb, out);
}

// Round 11
// 504.296 us; speedup vs baseline: 1.1668x; 1.0019x over previous
//
#include <hip/hip_runtime.h>
#include <stdint.h>

#define DD 256
#define NNODE 60000
#define MPAD 60032            // 469 * 128
#define NEDGE 200000
#define NGRAPH 1500
#define NCHUNK 59             // ceil(60000/1024)

typedef __bf16 bf16x8 __attribute__((ext_vector_type(8)));
typedef float f32x4 __attribute__((ext_vector_type(4)));
typedef unsigned short us8 __attribute__((ext_vector_type(8)));

__device__ __forceinline__ unsigned short f2bf(float f) {
    union { float f; unsigned int u; } v; v.f = f;
    unsigned int r = v.u + 0x7FFFu + ((v.u >> 16) & 1u);
    return (unsigned short)(r >> 16);
}
__device__ __forceinline__ float bf2f(unsigned short h) {
    union { unsigned int u; float f; } v; v.u = ((unsigned int)h) << 16;
    return v.f;
}
__device__ __forceinline__ void gload_lds16(const void* g, void* l) {
    __builtin_amdgcn_global_load_lds((const __attribute__((address_space(1))) void*)g,
                                     (__attribute__((address_space(3))) void*)l, 16, 0, 0);
}

// ---------------- weight prep: transposed bf16 weights ----------------
__global__ __launch_bounds__(256) void prep_weights(const float* __restrict__ mlpW,
                                                    const float* __restrict__ nnW,
                                                    const float* __restrict__ aW,
                                                    const float* __restrict__ ab,
                                                    unsigned short* __restrict__ wc1,
                                                    unsigned short* __restrict__ wc2,
                                                    unsigned short* __restrict__ nnt,
                                                    unsigned short* __restrict__ aWt) {
    int idx = blockIdx.x * 256 + threadIdx.x;
    if (idx < 256 * 512) {
        int n = idx >> 9, k = idx & 511;
        float v1 = (k < 256) ? mlpW[k * DD + n] : mlpW[(k + 256) * DD + n];
        wc1[idx] = f2bf(v1);
        wc2[idx] = f2bf(mlpW[(k + 256) * DD + n]);
    }
    if (idx < 256 * 256) {
        int n = idx >> 8, k = idx & 255;
        nnt[idx] = f2bf(nnW[k * DD + n]);
    }
    if (idx < 256 * 96) {
        int n = idx / 96, k = idx - n * 96;
        float v = (k < 92) ? aW[k * DD + n] : (k == 92 ? ab[n] : 0.0f);
        aWt[idx] = f2bf(v);
    }
}

// ---------------- u/v chains + BN fold ----------------
__global__ __launch_bounds__(256) void prep_uv(const float* __restrict__ eW, const float* __restrict__ eb,
                                               const float* __restrict__ mlpW, const float* __restrict__ mlpb,
                                               const float* __restrict__ nnb,
                                               const float* __restrict__ bn_g, const float* __restrict__ bn_b,
                                               const float* __restrict__ bn_m, const float* __restrict__ bn_v,
                                               float* __restrict__ u_all, float* __restrict__ v_all,
                                               float* __restrict__ scale, float* __restrict__ shift) {
    __shared__ float uc[DD], vc[DD];
    int d = threadIdx.x;
    uc[d] = eW[d];
    vc[d] = eb[d];
    float sc = bn_g[d] * rsqrtf(bn_v[d] + 1e-5f);
    scale[d] = sc;
    shift[d] = (nnb[d] - bn_m[d]) * sc + bn_b[d];
    __syncthreads();
    const float* W3 = mlpW + 2 * DD * DD;
    for (int it = 0; it < 4; ++it) {
        float su = 0.f, sv = 0.f;
        for (int k = 0; k < DD; ++k) {
            float w = W3[k * DD + d];
            su += uc[k] * w;
            sv += vc[k] * w;
        }
        sv += mlpb[d];
        u_all[it * DD + d] = su;
        v_all[it * DD + d] = sv;
        __syncthreads();
        uc[d] = su; vc[d] = sv;
        __syncthreads();
    }
}

// ---------------- nf -> bf16 padded [MPAD][96] with bias column ----------------
__global__ __launch_bounds__(256) void nfb_prep(const float* __restrict__ nf, unsigned short* __restrict__ nfb) {
    int idx = blockIdx.x * 256 + threadIdx.x;
    if (idx >= MPAD * 96) return;
    int r = idx / 96, c = idx - r * 96;
    float v;
    if (r < NNODE && c < 92) v = nf[(size_t)r * 92 + c];
    else v = (c == 92) ? 1.0f : 0.0f;
    nfb[idx] = f2bf(v);
}

// ---------------- xinit GEMM: x[M][256] = nfb[M][96] @ aWt^T, single-stage ----------------
__global__ __launch_bounds__(512) void xinit_gemm(const unsigned short* __restrict__ nfb,
                                                  const unsigned short* __restrict__ aWt,
                                                  unsigned short* __restrict__ x) {
    __shared__ unsigned short shmem[(128 + 256) * 96];
    unsigned short (*As)[96] = (unsigned short(*)[96])shmem;
    unsigned short (*Bs)[96] = (unsigned short(*)[96])(shmem + 128 * 96);
    const int tid = threadIdx.x;
    const int lane = tid & 63, wid = tid >> 6;
    const int wr = wid >> 2, wc = wid & 3;
    const int m0 = blockIdx.x * 128;
    const int lr = lane & 15, lq = lane >> 4;

    for (int i = tid; i < 128 * 12; i += 512) {
        int row = i / 12, ch = (i - row * 12) * 8;
        gload_lds16(nfb + (size_t)(m0 + row) * 96 + ch, &As[row][ch]);
    }
    for (int i = tid; i < 256 * 12; i += 512) {
        int row = i / 12, ch = (i - row * 12) * 8;
        gload_lds16(aWt + (size_t)row * 96 + ch, &Bs[row][ch]);
    }
    __syncthreads();

    f32x4 acc[4][4];
    #pragma unroll
    for (int m = 0; m < 4; ++m)
        #pragma unroll
        for (int n = 0; n < 4; ++n) { f32x4 z = {0.f,0.f,0.f,0.f}; acc[m][n] = z; }

    #pragma unroll
    for (int h = 0; h < 3; ++h) {
        bf16x8 af[4], bf[4];
        #pragma unroll
        for (int m = 0; m < 4; ++m)
            af[m] = *reinterpret_cast<const bf16x8*>(&As[wr * 64 + m * 16 + lr][h * 32 + lq * 8]);
        #pragma unroll
        for (int n = 0; n < 4; ++n)
            bf[n] = *reinterpret_cast<const bf16x8*>(&Bs[wc * 64 + n * 16 + lr][h * 32 + lq * 8]);
        #pragma unroll
        for (int m = 0; m < 4; ++m)
            #pragma unroll
            for (int n = 0; n < 4; ++n)
                acc[m][n] = __builtin_amdgcn_mfma_f32_16x16x32_bf16(af[m], bf[n], acc[m][n], 0, 0, 0);
    }
    __syncthreads();

    // LDS-staged coalesced epilogue
    unsigned short* stg = shmem;
    #pragma unroll
    for (int half = 0; half < 2; ++half) {
        if (wr == half) {
            #pragma unroll
            for (int m = 0; m < 4; ++m)
                #pragma unroll
                for (int n = 0; n < 4; ++n) {
                    const int cs = (wc * 64 + n * 16 + lr) ^ (lq << 4);
                    #pragma unroll
                    for (int j = 0; j < 4; ++j)
                        stg[(m * 16 + lq * 4 + j) * 256 + cs] = f2bf(acc[m][n][j]);
                }
        }
        __syncthreads();
        const int rbase = m0 + half * 64;
        #pragma unroll
        for (int t = 0; t < 4; ++t) {
            int tt = tid + t * 512;
            int rl = tt >> 5, ch = tt & 31;
            int chs = ch ^ (((rl >> 2) & 3) << 1);
            us8 pv = *(const us8*)&stg[rl * 256 + chs * 8];
            ((us8*)x)[(size_t)(rbase + rl) * 32 + ch] = pv;
        }
        __syncthreads();
    }
}

// ---------------- CSR build ----------------
__global__ __launch_bounds__(256) void hist_kernel(const int* __restrict__ ei, int* __restrict__ counts) {
    int e = blockIdx.x * 256 + threadIdx.x;
    if (e < NEDGE) atomicAdd(&counts[ei[NEDGE + e]], 1);
}

__global__ __launch_bounds__(256) void scan1(const int* __restrict__ counts, int* __restrict__ blockSums) {
    int t = threadIdx.x;
    int base = blockIdx.x * 1024 + t * 4;
    int s = 0;
    #pragma unroll
    for (int i = 0; i < 4; ++i) { int idx = base + i; if (idx < NNODE) s += counts[idx]; }
    __shared__ int red[256];
    red[t] = s; __syncthreads();
    for (int d = 128; d; d >>= 1) { if (t < d) red[t] += red[t + d]; __syncthreads(); }
    if (t == 0) blockSums[blockIdx.x] = red[0];
}

__global__ __launch_bounds__(64) void scan2(int* __restrict__ blockSums) {
    int t = threadIdx.x;
    int v = (t < NCHUNK) ? blockSums[t] : 0;
    int orig = v;
    #pragma unroll
    for (int d = 1; d < 64; d <<= 1) {
        int o = __shfl_up(v, d);
        if (t >= d) v += o;
    }
    if (t < NCHUNK) blockSums[t] = v - orig;   // exclusive
}

__global__ __launch_bounds__(256) void scan3(const int* __restrict__ counts, const int* __restrict__ blockSums,
                                             int* __restrict__ offsets, int* __restrict__ cursor) {
    int t = threadIdx.x;
    int base = blockIdx.x * 1024 + t * 4;
    int c[4]; int s = 0;
    #pragma unroll
    for (int i = 0; i < 4; ++i) { int idx = base + i; c[i] = (idx < NNODE) ? counts[idx] : 0; s += c[i]; }
    __shared__ int lds[256];
    lds[t] = s; __syncthreads();
    for (int d = 1; d < 256; d <<= 1) {
        int v = (t >= d) ? lds[t - d] : 0;
        __syncthreads();
        lds[t] += v;
        __syncthreads();
    }
    int off = blockSums[blockIdx.x] + lds[t] - s;
    #pragma unroll
    for (int i = 0; i < 4; ++i) {
        int idx = base + i;
        if (idx < NNODE) { offsets[idx] = off; cursor[idx] = off; off += c[i]; }
    }
}

__global__ __launch_bounds__(256) void scatter_kernel(const int* __restrict__ ei, const float* __restrict__ aw,
                                                      int* __restrict__ cursor,
                                                      int* __restrict__ srow, float* __restrict__ sw) {
    int e = blockIdx.x * 256 + threadIdx.x;
    if (e < NEDGE) {
        int c = ei[NEDGE + e];
        int pos = atomicAdd(&cursor[c], 1);
        srow[pos] = ei[e];
        sw[pos] = aw[e];
    }
}

// ---------------- merged P/Q GEMM, swizzled LDS, 48 KB, LDS-staged epilogue ----------------
// Twin mapping: bids 16p+{0..7} = P-half, 16p+{8..15} = Q-half of the SAME 8
// M-blocks; twin XCD = sub%8 = mb%8, matching the gemm_bn producer of x.
// Pout == nullptr (last layer): skip the dead P-state store (PX still written).
__global__ __launch_bounds__(512) void gemm_pq(const unsigned short* __restrict__ X,
                                               const unsigned short* __restrict__ Pst,
                                               const unsigned short* __restrict__ Qst,
                                               const unsigned short* __restrict__ B1,
                                               const unsigned short* __restrict__ B2,
                                               unsigned short* __restrict__ Pout,
                                               unsigned short* __restrict__ PXout,
                                               unsigned short* __restrict__ Qout,
                                               const float* __restrict__ cq,
                                               int Ktot) {
    __shared__ unsigned short shmem[(128 + 256) * 64];
    unsigned short (*As)[64] = (unsigned short(*)[64])shmem;
    unsigned short (*Bs)[64] = (unsigned short(*)[64])(shmem + 128 * 64);
    const int b = blockIdx.x;
    const int pairb = b >> 4, jj = b & 15;
    const int sel = jj >> 3, sub = jj & 7;
    const int mb = pairb * 8 + sub;
    if (mb >= MPAD / 128) return;
    const int m0 = mb * 128;

    const unsigned short* A1 = sel ? Qst : Pst;
    const unsigned short* Bt = sel ? B2 : B1;

    const int tid = threadIdx.x;
    const int lane = tid & 63, wid = tid >> 6;
    const int wr = wid >> 2, wc = wid & 3;
    const int lr = lane & 15, lq = lane >> 4;
    const int srow = tid >> 3;
    const int jphys = tid & 7;
    const int jlog = jphys ^ (srow & 7);
    const int scol_g = jlog * 8;
    const int scol_l = jphys * 8;
    const int xorj = (lr & 7);

    f32x4 acc[4][4];
    #pragma unroll
    for (int m = 0; m < 4; ++m)
        #pragma unroll
        for (int n = 0; n < 4; ++n) { f32x4 z = {0.f,0.f,0.f,0.f}; acc[m][n] = z; }

    const int nk = Ktot >> 6;
    for (int kt = 0; kt < nk; ++kt) {
        const int k0 = kt << 6;
        const unsigned short* Ap; int ka;
        if (k0 < 256) { Ap = X; ka = k0; } else { Ap = A1; ka = k0 - 256; }
        #pragma unroll
        for (int p = 0; p < 2; ++p) {
            int row = p * 64 + srow;
            gload_lds16(Ap + (size_t)(m0 + row) * DD + ka + scol_g, &As[row][scol_l]);
        }
        #pragma unroll
        for (int p = 0; p < 4; ++p) {
            int row = p * 64 + srow;
            gload_lds16(Bt + (size_t)row * 512 + k0 + scol_g, &Bs[row][scol_l]);
        }
        __syncthreads();
        #pragma unroll
        for (int h = 0; h < 2; ++h) {
            const int jp = ((h * 4 + lq) ^ xorj) * 8;
            bf16x8 af[4], bfr[4];
            #pragma unroll
            for (int m = 0; m < 4; ++m)
                af[m] = *reinterpret_cast<const bf16x8*>(&As[wr * 64 + m * 16 + lr][jp]);
            #pragma unroll
            for (int n = 0; n < 4; ++n)
                bfr[n] = *reinterpret_cast<const bf16x8*>(&Bs[wc * 64 + n * 16 + lr][jp]);
            #pragma unroll
            for (int m = 0; m < 4; ++m)
                #pragma unroll
                for (int n = 0; n < 4; ++n)
                    acc[m][n] = __builtin_amdgcn_mfma_f32_16x16x32_bf16(af[m], bfr[n], acc[m][n], 0, 0, 0);
        }
        __syncthreads();
    }

    // ---- LDS-staged coalesced epilogue ----
    float cqv[4];
    if (sel) {
        #pragma unroll
        for (int n = 0; n < 4; ++n) cqv[n] = cq[wc * 64 + n * 16 + lr];
    }
    unsigned short* stg = shmem;
    #pragma unroll
    for (int half = 0; half < 2; ++half) {
        if (wr == half) {
            #pragma unroll
            for (int m = 0; m < 4; ++m)
                #pragma unroll
                for (int n = 0; n < 4; ++n) {
                    const int cs = (wc * 64 + n * 16 + lr) ^ (lq << 4);
                    #pragma unroll
                    for (int j = 0; j < 4; ++j) {
                        float v = acc[m][n][j];
                        if (sel) v += cqv[n];
                        stg[(m * 16 + lq * 4 + j) * 256 + cs] = f2bf(v);
                    }
                }
        }
        __syncthreads();
        const int rbase = m0 + half * 64;
        #pragma unroll
        for (int t = 0; t < 4; ++t) {
            int tt = tid + t * 512;
            int rl = tt >> 5, ch = tt & 31;
            int chs = ch ^ (((rl >> 2) & 3) << 1);
            us8 pv = *(const us8*)&stg[rl * 256 + chs * 8];
            size_t gidx = (size_t)(rbase + rl) * 32 + ch;
            if (sel == 0) {
                us8 xv = ((const us8*)X)[gidx];
                us8 o;
                #pragma unroll
                for (int c = 0; c < 8; ++c) o[c] = f2bf(bf2f(pv[c]) + bf2f(xv[c]));
                if (Pout) ((us8*)Pout)[gidx] = pv;   // dead at last layer
                ((us8*)PXout)[gidx] = o;
            } else {
                ((us8*)Qout)[gidx] = pv;
            }
        }
        __syncthreads();
    }
}

// ---------------- BN GEMM: x = relu((aggB @ nnt^T) * scale + shift), staged epilogue ----------------
__global__ __launch_bounds__(512) void gemm_bn(const unsigned short* __restrict__ A,
                                               const unsigned short* __restrict__ Bt,
                                               unsigned short* __restrict__ Cout,
                                               const float* __restrict__ scale,
                                               const float* __restrict__ shift) {
    __shared__ unsigned short shmem[(128 + 256) * 64];
    unsigned short (*As)[64] = (unsigned short(*)[64])shmem;
    unsigned short (*Bs)[64] = (unsigned short(*)[64])(shmem + 128 * 64);
    const int tid = threadIdx.x;
    const int lane = tid & 63, wid = tid >> 6;
    const int wr = wid >> 2, wc = wid & 3;
    const int m0 = blockIdx.x * 128;
    const int lr = lane & 15, lq = lane >> 4;
    const int srow = tid >> 3;
    const int jphys = tid & 7;
    const int jlog = jphys ^ (srow & 7);
    const int scol_g = jlog * 8;
    const int scol_l = jphys * 8;
    const int xorj = (lr & 7);

    f32x4 acc[4][4];
    #pragma unroll
    for (int m = 0; m < 4; ++m)
        #pragma unroll
        for (int n = 0; n < 4; ++n) { f32x4 z = {0.f,0.f,0.f,0.f}; acc[m][n] = z; }

    for (int kt = 0; kt < 4; ++kt) {
        const int k0 = kt << 6;
        #pragma unroll
        for (int p = 0; p < 2; ++p) {
            int row = p * 64 + srow;
            gload_lds16(A + (size_t)(m0 + row) * DD + k0 + scol_g, &As[row][scol_l]);
        }
        #pragma unroll
        for (int p = 0; p < 4; ++p) {
            int row = p * 64 + srow;
            gload_lds16(Bt + (size_t)row * DD + k0 + scol_g, &Bs[row][scol_l]);
        }
        __syncthreads();
        #pragma unroll
        for (int h = 0; h < 2; ++h) {
            const int jp = ((h * 4 + lq) ^ xorj) * 8;
            bf16x8 af[4], bfr[4];
            #pragma unroll
            for (int m = 0; m < 4; ++m)
                af[m] = *reinterpret_cast<const bf16x8*>(&As[wr * 64 + m * 16 + lr][jp]);
            #pragma unroll
            for (int n = 0; n < 4; ++n)
                bfr[n] = *reinterpret_cast<const bf16x8*>(&Bs[wc * 64 + n * 16 + lr][jp]);
            #pragma unroll
            for (int m = 0; m < 4; ++m)
                #pragma unroll
                for (int n = 0; n < 4; ++n)
                    acc[m][n] = __builtin_amdgcn_mfma_f32_16x16x32_bf16(af[m], bfr[n], acc[m][n], 0, 0, 0);
        }
        __syncthreads();
    }

    float scl[4], shf[4];
    #pragma unroll
    for (int n = 0; n < 4; ++n) {
        int c = wc * 64 + n * 16 + lr;
        scl[n] = scale[c]; shf[n] = shift[c];
    }
    unsigned short* stg = shmem;
    #pragma unroll
    for (int half = 0; half < 2; ++half) {
        if (wr == half) {
            #pragma unroll
            for (int m = 0; m < 4; ++m)
                #pragma unroll
                for (int n = 0; n < 4; ++n) {
                    const int cs = (wc * 64 + n * 16 + lr) ^ (lq << 4);
                    #pragma unroll
                    for (int j = 0; j < 4; ++j) {
                        float y = fmaxf(acc[m][n][j] * scl[n] + shf[n], 0.f);
                        stg[(m * 16 + lq * 4 + j) * 256 + cs] = f2bf(y);
                    }
                }
        }
        __syncthreads();
        const int rbase = m0 + half * 64;
        #pragma unroll
        for (int t = 0; t < 4; ++t) {
            int tt = tid + t * 512;
            int rl = tt >> 5, ch = tt & 31;
            int chs = ch ^ (((rl >> 2) & 3) << 1);
            us8 pv = *(const us8*)&stg[rl * 256 + chs * 8];
            ((us8*)Cout)[(size_t)(rbase + rl) * 32 + ch] = pv;
        }
        __syncthreads();
    }
}

// ---------------- edge pass (CSR gather, XCD-aligned): one wave per node ----------------
// Node-group g (4 nodes) placed on XCD (g/32)%8, matching the gemm blocks that
// produce/consume rows 128*(g/32).. -> x/Qv reads and aggB writes stay L2-local.
// aggB[n] = x[n] + sum_{e: col(e)=n} relu( PX[r] + Qv[n] + w*u )
__global__ __launch_bounds__(256) void edge_csr(const int* __restrict__ offsets, const int* __restrict__ counts,
                                                const int* __restrict__ srow, const float* __restrict__ sw,
                                                const unsigned short* __restrict__ X,
                                                const unsigned short* __restrict__ PX,
                                                const unsigned short* __restrict__ Qv,
                                                const float* __restrict__ u,
                                                unsigned short* __restrict__ aggB) {
    const int lane = threadIdx.x & 63, wid = threadIdx.x >> 6;
    const int cls = blockIdx.x & 7;
    const int i = blockIdx.x >> 3;
    const int chunk = (i >> 5) * 8 + cls;
    const int g = chunk * 32 + (i & 31);
    const int n = g * 4 + wid;
    if (n >= NNODE) return;
    const int start = offsets[n];
    const int deg = counts[n];
    const int sub = lane & 31, h = lane >> 5;

    const us8* PX8 = (const us8*)PX;

    float4 u0 = ((const float4*)u)[sub * 2], u1 = ((const float4*)u)[sub * 2 + 1];
    float uu[8] = {u0.x, u0.y, u0.z, u0.w, u1.x, u1.y, u1.z, u1.w};

    us8 qv = ((const us8*)Qv)[(size_t)n * 32 + sub];
    float qb[8];
    #pragma unroll
    for (int c = 0; c < 8; ++c) qb[c] = bf2f(qv[c]);

    float a[8];
    us8 xv = ((const us8*)X)[(size_t)n * 32 + sub];
    #pragma unroll
    for (int c = 0; c < 8; ++c) a[c] = (h == 0) ? bf2f(xv[c]) : 0.f;

    for (int b0 = 0; b0 < deg; b0 += 64) {
        int m = deg - b0; if (m > 64) m = 64;
        int myr = 0; float myw = 0.f;
        if (lane < m) { myr = srow[start + b0 + lane]; myw = sw[start + b0 + lane]; }
        int iters = (m + 1) >> 1;
        for (int j = 0; j < iters; ++j) {
            int el = 2 * j + h;
            int r = __shfl(myr, el);
            float w = __shfl(myw, el);
            if (el < m) {
                us8 p2 = PX8[(size_t)r * 32 + sub];
                #pragma unroll
                for (int c = 0; c < 8; ++c)
                    a[c] += fmaxf(bf2f(p2[c]) + qb[c] + w * uu[c], 0.f);
            }
        }
    }
    #pragma unroll
    for (int c = 0; c < 8; ++c) a[c] += __shfl_xor(a[c], 32);
    if (h == 0) {
        us8 o;
        #pragma unroll
        for (int c = 0; c < 8; ++c) o[c] = f2bf(a[c]);
        ((us8*)aggB)[(size_t)n * 32 + sub] = o;
    }
}

// ---------------- pooling: pooled[batch[n]] += x[n], batch sorted ----------------
__global__ __launch_bounds__(256) void pool_kernel(const unsigned short* __restrict__ x,
                                                   const int* __restrict__ batch,
                                                   float* __restrict__ pooled) {
    const int lane = threadIdx.x & 63, wid = threadIdx.x >> 6;
    const int base = (blockIdx.x * 4 + wid) * 8;
    float4 acc = make_float4(0.f, 0.f, 0.f, 0.f);
    int gcur = -1;
    for (int i = 0; i < 8; ++i) {
        int n = base + i;
        if (n >= NNODE) break;
        int g = batch[n];
        if (g != gcur) {
            if (gcur >= 0) {
                float* pp = pooled + (size_t)gcur * DD + lane * 4;
                unsafeAtomicAdd(pp + 0, acc.x);
                unsafeAtomicAdd(pp + 1, acc.y);
                unsafeAtomicAdd(pp + 2, acc.z);
                unsafeAtomicAdd(pp + 3, acc.w);
            }
            gcur = g;
            acc = make_float4(0.f, 0.f, 0.f, 0.f);
        }
        ushort4 xv = ((const ushort4*)x)[(size_t)n * 64 + lane];
        acc.x += bf2f(xv.x); acc.y += bf2f(xv.y);
        acc.z += bf2f(xv.z); acc.w += bf2f(xv.w);
    }
    if (gcur >= 0) {
        float* pp = pooled + (size_t)gcur * DD + lane * 4;
        unsafeAtomicAdd(pp + 0, acc.x);
        unsafeAtomicAdd(pp + 1, acc.y);
        unsafeAtomicAdd(pp + 2, acc.z);
        unsafeAtomicAdd(pp + 3, acc.w);
    }
}

// ---------------- out: d_out = pooled @ outW + outb ----------------
__global__ __launch_bounds__(64) void out_kernel(const float* __restrict__ pooled,
                                                 const float* __restrict__ outW,
                                                 const float* __restrict__ outb,
                                                 float* __restrict__ out) {
    const int g = blockIdx.x, lane = threadIdx.x;
    float4 p = ((const float4*)pooled)[g * 64 + lane];
    float s[6];
    #pragma unroll
    for (int j = 0; j < 6; ++j) {
        float a = p.x * outW[(lane * 4 + 0) * 6 + j] + p.y * outW[(lane * 4 + 1) * 6 + j] +
                  p.z * outW[(lane * 4 + 2) * 6 + j] + p.w * outW[(lane * 4 + 3) * 6 + j];
        #pragma unroll
        for (int off = 32; off; off >>= 1) a += __shfl_down(a, off);
        s[j] = a;
    }
    if (lane == 0) {
        #pragma unroll
        for (int j = 0; j < 6; ++j) out[g * 6 + j] = s[j] + outb[j];
    }
}

extern "C" void kernel_launch(void* const* d_in, const int* in_sizes, int n_in,
                              void* d_out, int out_size, void* d_ws, size_t ws_size,
                              hipStream_t stream) {
    const float* nf    = (const float*)d_in[0];
    const int*   ei    = (const int*)d_in[1];
    const float* aw    = (const float*)d_in[2];
    const int*   batch = (const int*)d_in[3];
    const float* aW    = (const float*)d_in[4];
    const float* ab    = (const float*)d_in[5];
    const float* eW    = (const float*)d_in[6];
    const float* eb    = (const float*)d_in[7];
    const float* mlpW  = (const float*)d_in[8];
    const float* mlpb  = (const float*)d_in[9];
    const float* nnW   = (const float*)d_in[10];
    const float* nnb   = (const float*)d_in[11];
    const float* bn_g  = (const float*)d_in[12];
    const float* bn_b  = (const float*)d_in[13];
    const float* bn_m  = (const float*)d_in[14];
    const float* bn_v  = (const float*)d_in[15];
    const float* outW  = (const float*)d_in[16];
    const float* outb  = (const float*)d_in[17];
    float* out = (float*)d_out;

    char* ws = (char*)d_ws;
    size_t off = 0;
    auto alloc = [&](size_t bytes) -> void* {
        void* p = ws + off;
        off += (bytes + 255) & ~(size_t)255;
        return p;
    };
    unsigned short* x    = (unsigned short*)alloc((size_t)MPAD * DD * 2);
    unsigned short* P    = (unsigned short*)alloc((size_t)MPAD * DD * 2);
    unsigned short* Qv   = (unsigned short*)alloc((size_t)MPAD * DD * 2);
    unsigned short* aggB = (unsigned short*)alloc((size_t)MPAD * DD * 2);
    // PX shares its region with nfb (nfb dead after xinit; PX written from layer 0 on)
    unsigned short* PX   = (unsigned short*)alloc((size_t)MPAD * DD * 2);
    unsigned short* nfb  = PX;   // MPAD*96*2 < MPAD*DD*2, alias is safe
    unsigned short* wc1  = (unsigned short*)alloc(256 * 512 * 2);
    unsigned short* wc2  = (unsigned short*)alloc(256 * 512 * 2);
    unsigned short* nnt  = (unsigned short*)alloc(256 * 256 * 2);
    unsigned short* aWt  = (unsigned short*)alloc(256 * 96 * 2);
    float* u_all = (float*)alloc(4 * DD * 4);
    float* v_all = (float*)alloc(4 * DD * 4);
    float* scale = (float*)alloc(DD * 4);
    float* shift = (float*)alloc(DD * 4);
    float* pooled = (float*)alloc((size_t)NGRAPH * DD * 4);
    int* counts  = (int*)alloc((size_t)NNODE * 4);
    int* offsets = (int*)alloc((size_t)NNODE * 4);
    int* cursor  = (int*)alloc((size_t)NNODE * 4);
    int* blockSums = (int*)alloc(NCHUNK * 4);
    int* srowB   = (int*)alloc((size_t)NEDGE * 4);
    float* swB   = (float*)alloc((size_t)NEDGE * 4);
    (void)ws_size; (void)in_sizes; (void)n_in; (void)out_size;

    // one-time prep
    prep_weights<<<512, 256, 0, stream>>>(mlpW, nnW, aW, ab, wc1, wc2, nnt, aWt);
    prep_uv<<<1, 256, 0, stream>>>(eW, eb, mlpW, mlpb, nnb, bn_g, bn_b, bn_m, bn_v,
                                   u_all, v_all, scale, shift);
    nfb_prep<<<(MPAD * 96 + 255) / 256, 256, 0, stream>>>(nf, nfb);
    xinit_gemm<<<MPAD / 128, 512, 0, stream>>>(nfb, aWt, x);

    // CSR build (once; shared by all 4 layers)
    hipMemsetAsync(counts, 0, (size_t)NNODE * 4, stream);
    hist_kernel<<<(NEDGE + 255) / 256, 256, 0, stream>>>(ei, counts);
    scan1<<<NCHUNK, 256, 0, stream>>>(counts, blockSums);
    scan2<<<1, 64, 0, stream>>>(blockSums);
    scan3<<<NCHUNK, 256, 0, stream>>>(counts, blockSums, offsets, cursor);
    scatter_kernel<<<(NEDGE + 255) / 256, 256, 0, stream>>>(ei, aw, cursor, srowB, swB);

    const int npairs = (MPAD / 128 + 7) / 8;   // 59
    const int edge_blocks = 8 * 59 * 32;
    for (int k = 0; k < 4; ++k) {
        gemm_pq<<<npairs * 16, 512, 0, stream>>>(x, P, Qv, wc1, wc2,
                                                 (k == 3) ? nullptr : P, PX, Qv,
                                                 k == 0 ? v_all : mlpb, k ? 512 : 256);
        edge_csr<<<edge_blocks, 256, 0, stream>>>(offsets, counts, srowB, swB, x, PX, Qv,
                                                  u_all + k * DD, aggB);
        gemm_bn<<<MPAD / 128, 512, 0, stream>>>(aggB, nnt, x, scale, shift);
    }

    hipMemsetAsync(pooled, 0, (size_t)NGRAPH * DD * 4, stream);
    pool_kernel<<<(NNODE + 31) / 32, 256, 0, stream>>>(x, batch, pooled);
    out_kernel<<<NGRAPH, 64, 0, stream>>>(pooled, outW, outb, out);
}